// Round 9
// baseline (212.917 us; speedup 1.0000x reference)
//
#include <hip/hip_runtime.h>

typedef float f32x4 __attribute__((ext_vector_type(4)));
typedef float f32x16 __attribute__((ext_vector_type(16)));
typedef _Float16 f16;
typedef _Float16 f16x2 __attribute__((ext_vector_type(2)));
typedef _Float16 f16x8 __attribute__((ext_vector_type(8)));
typedef unsigned int u32x2 __attribute__((ext_vector_type(2)));
typedef unsigned short u16;
typedef unsigned short u16x4 __attribute__((ext_vector_type(4)));
typedef unsigned int u32;

#define S_LEN 2048
#define NHEAD 16
#define DHEAD 64
#define DMODEL 1024
#define NBATCH 4

__device__ __forceinline__ void gload16(const u16* g, const uint4* l) {
  __builtin_amdgcn_global_load_lds((const __attribute__((address_space(1))) void*)g,
                                   (__attribute__((address_space(3))) void*)l, 16, 0, 0);
}

// exp path: whole chain builtin-visible (exp2f -> cvt_pkrtz -> MFMA). Raw v_exp_f32
// or builtin-exp2 feeding inline-ASM consumers corrupts (r7/r9).
// R3/R5 ROOT CAUSE (found R6): permlane32_swap(x, x) with the SAME register for both
// operands degenerates. Merge partner halves with __shfl_xor instead.
// R7 lesson: chained dot2 accumulators cost ~3us latency -> split 4-way.
// R8 lesson: 4 structurally different attn loops all land 83-86us; per-iter cycle
// budget sums to measured time -> pipes are SERIALIZED; only removing total demand
// helps. R9: K taken out of LDS entirely (direct global->VGPR, prefetched 1 iter
// ahead, L1/L2-resident) -- LDS demand -40%, QK^T loses its LDS dependency.

__device__ __forceinline__ float dot2acc(u32 a, u32 b, float c) {
#if __has_builtin(__builtin_amdgcn_fdot2)
  return __builtin_amdgcn_fdot2(__builtin_bit_cast(f16x2, a), __builtin_bit_cast(f16x2, b), c, false);
#else
  f16x2 pa = __builtin_bit_cast(f16x2, a), pb = __builtin_bit_cast(f16x2, b);
  return c + (float)pa[0] * (float)pb[0] + (float)pa[1] * (float)pb[1];
#endif
}

// ---------------- convert x (f32 -> f16), packed ----------------
__global__ void cvt_x(const float* __restrict__ x, u16* __restrict__ o, int n4) {
  int i = blockIdx.x * blockDim.x + threadIdx.x;
  int st = gridDim.x * blockDim.x;
  for (; i < n4; i += st) {
    float4 v = reinterpret_cast<const float4*>(x)[i];
    uint2 r;
    r.x = __builtin_bit_cast(u32, __builtin_amdgcn_cvt_pkrtz(v.x, v.y));
    r.y = __builtin_bit_cast(u32, __builtin_amdgcn_cvt_pkrtz(v.z, v.w));
    reinterpret_cast<uint2*>(o)[i] = r;
  }
}

// ---------------- transpose W: f32 [K][N] -> f16 [N][K] ----------------
__global__ void trans_w(const float* __restrict__ W, u16* __restrict__ wt) {
  __shared__ float t[32][33];
  int bx = blockIdx.x * 32, by = blockIdx.y * 32;
  int tx = threadIdx.x & 31, ty = threadIdx.x >> 5;  // ty in 0..7
#pragma unroll
  for (int i = 0; i < 32; i += 8)
    t[ty + i][tx] = W[(size_t)(by + ty + i) * DMODEL + bx + tx];
  __syncthreads();
#pragma unroll
  for (int i = 0; i < 32; i += 8)
    wt[(size_t)(bx + ty + i) * DMODEL + by + tx] = __builtin_bit_cast(u16, (f16)t[tx][ty + i]);
}

// ---------------- fused QKV projection GEMM ----------------
// Round-0 envelope (proven): 128x128 tile, BK=32, 4 waves, 48KB LDS, 3 blocks/CU,
// grid (64,24)=1536 blocks -> exactly 2 full scheduling rounds.
// 32x32x16 MFMA engine, acc[2][2] f32x16 (64 AGPR), 8 ds_read_b128/iter.
// 3-buf counted-vmcnt pipeline: {vmcnt(4) -> barrier -> stage(it+2) -> ds_read
// -> 8 MFMA}. Stage staying in flight across the barrier (T4).
__global__ __launch_bounds__(256) void qkv_gemm(
    const u16* __restrict__ A, const u16* __restrict__ Wt,
    const float* __restrict__ bq, const float* __restrict__ bk, const float* __restrict__ bv,
    const float* __restrict__ mask,
    u16* __restrict__ Qo, u16* __restrict__ Ko, u16* __restrict__ Vo)
{
  __shared__ uint4 As4[3][512];   // [128 rows][4 slots] per buffer
  __shared__ uint4 Bs4[3][512];
  const int tid = threadIdx.x;
  const int lane = tid & 63;
  const int wid = tid >> 6;
  const int l31 = lane & 31, hi = lane >> 5;
  const int m0 = blockIdx.x * 128;
  const int n0 = blockIdx.y * 128;
  const int wr = (wid >> 1) * 64, wc = (wid & 1) * 64;

  f32x16 acc[2][2] = {};

  // glds geometry: wave w stages phys chunks w*64+lane, +256.
  // phys chunk c = row*4 + p; stored data = logical slot l = p ^ ((row>>1)&3).
  const int c0 = wid * 64 + lane, c1 = c0 + 256;
  const int r0 = c0 >> 2, r1 = c1 >> 2;
  const int p4 = lane & 3;
  const int sl0 = p4 ^ ((r0 >> 1) & 3);
  const int sl1 = p4 ^ ((r1 >> 1) & 3);
  const u16* ag0 = A  + (size_t)(m0 + r0) * 1024 + sl0 * 8;
  const u16* ag1 = A  + (size_t)(m0 + r1) * 1024 + sl1 * 8;
  const u16* bg0 = Wt + (size_t)(n0 + r0) * 1024 + sl0 * 8;
  const u16* bg1 = Wt + (size_t)(n0 + r1) * 1024 + sl1 * 8;

  auto stage = [&](int buf, int kt) {
    gload16(ag0 + kt, &As4[buf][wid * 64]);
    gload16(ag1 + kt, &As4[buf][wid * 64 + 256]);
    gload16(bg0 + kt, &Bs4[buf][wid * 64]);
    gload16(bg1 + kt, &Bs4[buf][wid * 64 + 256]);
  };

  // iteration-invariant LDS read offsets (u16 units)
  int aoff[2][2], boff[2][2];
#pragma unroll
  for (int mi = 0; mi < 2; mi++) {
    int r = wr + mi * 32 + l31;
#pragma unroll
    for (int ks = 0; ks < 2; ks++)
      aoff[mi][ks] = r * 32 + (((ks * 2 + hi) ^ ((r >> 1) & 3)) * 8);
  }
#pragma unroll
  for (int ni = 0; ni < 2; ni++) {
    int r = wc + ni * 32 + l31;
#pragma unroll
    for (int ks = 0; ks < 2; ks++)
      boff[ni][ks] = r * 32 + (((ks * 2 + hi) ^ ((r >> 1) & 3)) * 8);
  }

  stage(0, 0);
  stage(1, 32);
  __syncthreads();              // one-time full drain: buf0+buf1 resident

  const int NT = 1024 / 32;
  for (int it = 0; it < NT; ++it) {
    if (it + 1 < NT) asm volatile("s_waitcnt vmcnt(4)" ::: "memory");
    else             asm volatile("s_waitcnt vmcnt(0)" ::: "memory");
    __builtin_amdgcn_s_barrier();
    __builtin_amdgcn_sched_barrier(0);
    const int cur = it % 3;
    if (it + 2 < NT) stage((it + 2) % 3, (it + 2) * 32);   // stays in flight past barrier

    const u16* As = (const u16*)&As4[cur][0];
    const u16* Bs = (const u16*)&Bs4[cur][0];
    f16x8 af[2][2], bf[2][2];
#pragma unroll
    for (int mi = 0; mi < 2; mi++)
#pragma unroll
      for (int ks = 0; ks < 2; ks++)
        af[mi][ks] = *(const f16x8*)&As[aoff[mi][ks]];
#pragma unroll
    for (int ni = 0; ni < 2; ni++)
#pragma unroll
      for (int ks = 0; ks < 2; ks++)
        bf[ni][ks] = *(const f16x8*)&Bs[boff[ni][ks]];

#pragma unroll
    for (int ks = 0; ks < 2; ks++)
#pragma unroll
      for (int mi = 0; mi < 2; mi++)
#pragma unroll
        for (int ni = 0; ni < 2; ni++)
          acc[mi][ni] = __builtin_amdgcn_mfma_f32_32x32x16_f16(af[mi][ks], bf[ni][ks], acc[mi][ni], 0, 0, 0);
  }

  // ---- epilogue: scatter into Q/K/V layouts ----
  const int sel = n0 >> 10;                    // 0:Q 1:K 2:V
  const float* bias = (sel == 0) ? bq : (sel == 1) ? bk : bv;
  const int nbase = (n0 & 1023) + wc;
  const float QSCALE = 0.18033688011112042f;   // log2(e)/8  (exp2-domain softmax)
#pragma unroll
  for (int mi = 0; mi < 2; mi++)
#pragma unroll
    for (int ni = 0; ni < 2; ni++) {
      const int ncol = nbase + ni * 32 + l31;
      const float bi = bias[ncol];
      const int h = ncol >> 6, dh = ncol & 63;
#pragma unroll
      for (int r4 = 0; r4 < 4; r4++) {
        // C layout (32x32): col = lane&31, row = (reg&3) + 8*(reg>>2) + 4*(lane>>5)
        const int rowb = m0 + wr + mi * 32 + 8 * r4 + 4 * hi;
        const int bb = rowb >> 11, s0 = rowb & 2047;
        const size_t bh = (size_t)(bb * NHEAD + h);
        if (sel == 0) {
#pragma unroll
          for (int j = 0; j < 4; j++)
            Qo[(bh * S_LEN + s0 + j) * DHEAD + dh] =
                __builtin_bit_cast(u16, (f16)((acc[mi][ni][r4 * 4 + j] + bi) * QSCALE));
        } else if (sel == 1) {
#pragma unroll
          for (int j = 0; j < 4; j++)
            Ko[(bh * S_LEN + s0 + j) * DHEAD + dh] =
                __builtin_bit_cast(u16, (f16)(acc[mi][ni][r4 * 4 + j] + bi));
        } else {
          const float4 mk = *(const float4*)&mask[bb * S_LEN + s0];   // s0 % 4 == 0
          u16x4 pk;
#pragma unroll
          for (int j = 0; j < 4; j++) {
            float v = acc[mi][ni][r4 * 4 + j] + bi;
            float mj = (j == 0) ? mk.x : (j == 1) ? mk.y : (j == 2) ? mk.z : mk.w;
            if (mj <= 0.f) v = 0.f;            // fold mask into V
            pk[j] = __builtin_bit_cast(u16, (f16)v);
          }
          *(u16x4*)&Vo[(bh * DHEAD + dh) * S_LEN + s0] = pk;  // 4 consecutive s -> 8B store
        }
      }
    }
}

// ---------------- flash attention: swapped-QK^T 32x32 f16, K-in-registers ----------------
// grid 512; 4 waves/block, wave owns q rows q0..q0+63 (two 32-subtiles).
// ROUND 9: K is NOT staged in LDS. Each wave loads its own K fragments directly
// global->VGPR, prefetched ONE ITERATION ahead (issued right after the barrier,
// consumed next iter: ~6000cyc slack vs ~200cyc L2 latency; K tile is 8KB,
// L1/L2-resident, re-read by 4 waves/block + 8 blocks/bh). Effects:
//   * LDS reads/wave-iter 20 -> 12 (V 8 + mask 4); gload_lds 4 -> 2.
//   * K-read bank conflicts gone.
//   * QK^T has ZERO LDS dependency -- 16 MFMAs issue at iter start while
//     phaseB's V/mask ds_reads flow in parallel (de-serializes the pipes).
// LDS 53 -> 28 KB. V staging + 3-buf vmcnt(0) discipline unchanged (proven).
// dot2 denominator w/ split accumulators + shfl_xor/ds_bpermute epilogue (proven).
__global__ __launch_bounds__(256, 2) void attn(
    const u16* __restrict__ Q, const u16* __restrict__ K, const u16* __restrict__ Vt,
    const float* __restrict__ mask, float* __restrict__ out)
{
  __shared__ uint4 Vs4[3][512];                // [d=64][slot=8] skewed (V^T)
  __shared__ __align__(16) u16 MsAll[S_LEN];   // whole mask row as f16 (4KB)
  const int tid = threadIdx.x;
  const int lane = tid & 63, wid = tid >> 6;
  const int l31 = lane & 31, hi = lane >> 5;
  const int sid = blockIdx.x;
  const int qt = (sid >> 3) & 7;
  const int bh = (sid & 7) + 8 * (sid >> 6);
  const int b = bh >> 4, h = bh & 15;
  const size_t base = (size_t)bh * S_LEN * DHEAD;
  const u16* Qp = Q + base;
  const u16* Kp = K + base;
  const u16* Vp = Vt + base;                   // [d][s]
  const float* mp = mask + b * S_LEN;
  const int q0 = qt * 256 + wid * 64;

  // Q as B-fragments for the two 32-row subtiles
  f16x8 aqA[4], aqB[4];
#pragma unroll
  for (int kc = 0; kc < 4; kc++) {
    aqA[kc] = *(const f16x8*)&Qp[(size_t)(q0 + l31) * DHEAD + kc * 16 + hi * 8];
    aqB[kc] = *(const f16x8*)&Qp[(size_t)(q0 + 32 + l31) * DHEAD + kc * 16 + hi * 8];
  }

  f32x16 accO0A = {}, accO1A = {};
  f32x16 accO0B = {}, accO1B = {};
  float lAp[4] = {0.f, 0.f, 0.f, 0.f};         // split denominator partials
  float lBp[4] = {0.f, 0.f, 0.f, 0.f};

  // V staging geometry (G21: linear LDS dest, inverse-skewed global source)
  const int cA_ = wid * 128 + lane, cB_ = cA_ + 64;
  const int rk0 = cA_ >> 3, rk1 = cB_ >> 3;
  const int p8 = lane & 7;
  const int cc0 = (p8 - ((rk0 + (rk0 >> 3)) & 7)) & 7;
  const int cc1 = (p8 - ((rk1 + (rk1 >> 3)) & 7)) & 7;
  const u16* vg0 = Vp + (size_t)rk0 * S_LEN + cc0 * 8;
  const u16* vg1 = Vp + (size_t)rk1 * S_LEN + cc1 * 8;

  auto stage = [&](int buf) {
    gload16(vg0, &Vs4[buf][wid * 128]); gload16(vg1, &Vs4[buf][wid * 128 + 64]);
    vg0 += 64; vg1 += 64;
  };

  // LDS read slot table (V's g-loop)
  const int swA = (l31 + (l31 >> 3)) & 7;
  const int swB = (swA + 4) & 7;
  int idxA[4], idxB[4];
#pragma unroll
  for (int kc = 0; kc < 4; kc++) {
    idxA[kc] = l31 * 8 + ((kc * 2 + hi + swA) & 7);
    idxB[kc] = (32 + l31) * 8 + ((kc * 2 + hi + swB) & 7);
  }

  // K direct-load base: fragment (kc, half) of tile it lives at
  //   kq + it*4096 + half*2048 + kc*16   (elements; = K[it*64+half*32+l31][kc*16+hi*8])
  const u16* kq = Kp + l31 * DHEAD + hi * 8;

  // one-time mask preload (f32 -> f16, 8 values/thread)
  {
    float4 ml0 = *(const float4*)&mp[tid * 8];
    float4 ml1 = *(const float4*)&mp[tid * 8 + 4];
    uint4 w;
    w.x = __builtin_bit_cast(u32, __builtin_amdgcn_cvt_pkrtz(ml0.x, ml0.y));
    w.y = __builtin_bit_cast(u32, __builtin_amdgcn_cvt_pkrtz(ml0.z, ml0.w));
    w.z = __builtin_bit_cast(u32, __builtin_amdgcn_cvt_pkrtz(ml1.x, ml1.y));
    w.w = __builtin_bit_cast(u32, __builtin_amdgcn_cvt_pkrtz(ml1.z, ml1.w));
    *(uint4*)&MsAll[tid * 8] = w;
  }
  // prologue: V(0), V(1) to LDS; K(0) to registers
  stage(0);
  stage(1);
  f16x8 kr[4][2];
#pragma unroll
  for (int kc = 0; kc < 4; kc++) {
    kr[kc][0] = *(const f16x8*)(kq + kc * 16);
    kr[kc][1] = *(const f16x8*)(kq + 2048 + kc * 16);
  }
  __syncthreads();              // full drain: V bufs + MsAll resident, kr landed

  const int NT = S_LEN / 64;
  for (int it = 0; it < NT; ++it) {
    asm volatile("s_waitcnt vmcnt(0)" ::: "memory");   // V(it) in LDS (own-wave part)
    __builtin_amdgcn_s_barrier();                      // all waves' stages visible
    __builtin_amdgcn_sched_barrier(0);
    const int cur = it % 3;
    const uint4* vs = &Vs4[cur][0];
    if (it + 2 < NT) stage((it + 2) % 3);              // V prefetch, flies under body

    // K(it+1) prefetch -> krn (consumed next iteration; latency hides under body)
    f16x8 krn[4][2];
    if (it + 1 < NT) {
      const u16* kqn = kq + (it + 1) * 4096;
#pragma unroll
      for (int kc = 0; kc < 4; kc++) {
        krn[kc][0] = *(const f16x8*)(kqn + kc * 16);
        krn[kc][1] = *(const f16x8*)(kqn + 2048 + kc * 16);
      }
    }

    // ---- S^T = K Q^T from REGISTERS (no LDS dependency) ----
    f32x16 sA0 = {}, sA1 = {}, sB0 = {}, sB1 = {};
#pragma unroll
    for (int kc = 0; kc < 4; kc++) {
      sA0 = __builtin_amdgcn_mfma_f32_32x32x16_f16(kr[kc][0], aqA[kc], sA0, 0, 0, 0);
      sA1 = __builtin_amdgcn_mfma_f32_32x32x16_f16(kr[kc][1], aqA[kc], sA1, 0, 0, 0);
      sB0 = __builtin_amdgcn_mfma_f32_32x32x16_f16(kr[kc][0], aqB[kc], sB0, 0, 0, 0);
      sB1 = __builtin_amdgcn_mfma_f32_32x32x16_f16(kr[kc][1], aqB[kc], sB1, 0, 0, 0);
    }

    // ---- fused p=exp2(S) -> f16 pack -> permlane -> PV + dot2 denominator ----
#pragma unroll
    for (int g = 0; g < 4; g++) {
      const f32x16& srcA = (g < 2) ? sA0 : sA1;
      const f32x16& srcB = (g < 2) ? sB0 : sB1;
      const int o = (g & 1) * 8;
      u32 wa[4], wb[4];
#pragma unroll
      for (int s = 0; s < 4; s++) {
        wa[s] = __builtin_bit_cast(u32, __builtin_amdgcn_cvt_pkrtz(
                    __builtin_amdgcn_exp2f(srcA[o + 2 * s]),
                    __builtin_amdgcn_exp2f(srcA[o + 2 * s + 1])));
        wb[s] = __builtin_bit_cast(u32, __builtin_amdgcn_cvt_pkrtz(
                    __builtin_amdgcn_exp2f(srcB[o + 2 * s]),
                    __builtin_amdgcn_exp2f(srcB[o + 2 * s + 1])));
      }
      u32x2 rA0 = __builtin_amdgcn_permlane32_swap(wa[0], wa[2], false, false);
      u32x2 rA1 = __builtin_amdgcn_permlane32_swap(wa[1], wa[3], false, false);
      u32x2 rB0 = __builtin_amdgcn_permlane32_swap(wb[0], wb[2], false, false);
      u32x2 rB1 = __builtin_amdgcn_permlane32_swap(wb[1], wb[3], false, false);
      uint4 f4A; f4A.x = rA0[0]; f4A.y = rA1[0]; f4A.z = rA0[1]; f4A.w = rA1[1];
      uint4 f4B; f4B.x = rB0[0]; f4B.y = rB1[0]; f4B.z = rB0[1]; f4B.w = rB1[1];
      f16x8 fA = __builtin_bit_cast(f16x8, f4A);
      f16x8 fB = __builtin_bit_cast(f16x8, f4B);
      f16x8 bv0 = *(const f16x8*)&vs[idxA[g]];
      f16x8 bv1 = *(const f16x8*)&vs[idxB[g]];
      const uint4 bmw = *(const uint4*)&MsAll[it * 64 + g * 16 + hi * 8];
      accO0A = __builtin_amdgcn_mfma_f32_32x32x16_f16(fA, bv0, accO0A, 0, 0, 0);
      accO1A = __builtin_amdgcn_mfma_f32_32x32x16_f16(fA, bv1, accO1A, 0, 0, 0);
      accO0B = __builtin_amdgcn_mfma_f32_32x32x16_f16(fB, bv0, accO0B, 0, 0, 0);
      accO1B = __builtin_amdgcn_mfma_f32_32x32x16_f16(fB, bv1, accO1B, 0, 0, 0);
      lAp[0] = dot2acc(f4A.x, bmw.x, lAp[0]);
      lAp[1] = dot2acc(f4A.y, bmw.y, lAp[1]);
      lAp[2] = dot2acc(f4A.z, bmw.z, lAp[2]);
      lAp[3] = dot2acc(f4A.w, bmw.w, lAp[3]);
      lBp[0] = dot2acc(f4B.x, bmw.x, lBp[0]);
      lBp[1] = dot2acc(f4B.y, bmw.y, lBp[1]);
      lBp[2] = dot2acc(f4B.z, bmw.z, lBp[2]);
      lBp[3] = dot2acc(f4B.w, bmw.w, lBp[3]);
    }

    // rotate K prefetch into place (register rename, no real copy)
#pragma unroll
    for (int kc = 0; kc < 4; kc++) { kr[kc][0] = krn[kc][0]; kr[kc][1] = krn[kc][1]; }
  }

  // ---- epilogue ----
  // merge split partials, then partner t-half via __shfl_xor (NOT permlane32_swap(x,x)).
  float lA = (lAp[0] + lAp[1]) + (lAp[2] + lAp[3]);
  float lB = (lBp[0] + lBp[1]) + (lBp[2] + lBp[3]);
  float lAf = lA + __shfl_xor(lA, 32, 64);
  float lBf = lB + __shfl_xor(lB, 32, 64);
  float invA = (lAf > 0.f) ? 1.f / lAf : 0.f;   // lane holds 1/l for q = l31
  float invB = (lBf > 0.f) ? 1.f / lBf : 0.f;
#pragma unroll
  for (int r = 0; r < 16; r++) {
    int qr = (r & 3) + 8 * (r >> 2) + 4 * hi;
    float iA = __builtin_bit_cast(float,
        (u32)__builtin_amdgcn_ds_bpermute(qr << 2, (int)__builtin_bit_cast(u32, invA)));
    float iB = __builtin_bit_cast(float,
        (u32)__builtin_amdgcn_ds_bpermute(qr << 2, (int)__builtin_bit_cast(u32, invB)));
    float* opA = out + ((size_t)(b * S_LEN + q0 + qr) * DMODEL) + h * DHEAD;
    float* opB = out + ((size_t)(b * S_LEN + q0 + 32 + qr) * DMODEL) + h * DHEAD;
    opA[l31] = accO0A[r] * iA;
    opA[32 + l31] = accO1A[r] * iA;
    opB[l31] = accO0B[r] * iB;
    opB[32 + l31] = accO1B[r] * iB;
  }
}

extern "C" void kernel_launch(void* const* d_in, const int* in_sizes, int n_in,
                              void* d_out, int out_size, void* d_ws, size_t ws_size,
                              hipStream_t stream) {
  const float* x    = (const float*)d_in[0];
  const float* mask = (const float*)d_in[1];
  const float* Wq   = (const float*)d_in[2];
  const float* bq   = (const float*)d_in[3];
  const float* Wk   = (const float*)d_in[4];
  const float* bk   = (const float*)d_in[5];
  const float* Wv   = (const float*)d_in[6];
  const float* bv   = (const float*)d_in[7];
  float* out = (float*)d_out;

  u16* xb = (u16*)d_ws;                         // [8192][1024] f16
  u16* wt = xb + (size_t)8192 * 1024;           // [3072][1024] f16 (W^T, q|k|v)
  u16* Qb = wt + (size_t)3072 * 1024;           // [4][16][2048][64]
  u16* Kb = Qb + (size_t)8388608;               // [4][16][2048][64]
  u16* Vb = Kb + (size_t)8388608;               // [4][16][64][2048] (mask-zeroed)

  cvt_x<<<2048, 256, 0, stream>>>(x, xb, (8192 * 1024) / 4);
  trans_w<<<dim3(32, 32), 256, 0, stream>>>(Wq, wt);
  trans_w<<<dim3(32, 32), 256, 0, stream>>>(Wk, wt + (size_t)1024 * 1024);
  trans_w<<<dim3(32, 32), 256, 0, stream>>>(Wv, wt + (size_t)2 * 1024 * 1024);
  qkv_gemm<<<dim3(64, 24), 256, 0, stream>>>(xb, wt, bq, bk, bv, mask, Qb, Kb, Vb);
  attn<<<512, 256, 0, stream>>>(Qb, Kb, Vb, mask, out);
}

// Round 10
// 196.692 us; speedup vs baseline: 1.0825x; 1.0825x over previous
//
#include <hip/hip_runtime.h>

typedef float f32x4 __attribute__((ext_vector_type(4)));
typedef float f32x16 __attribute__((ext_vector_type(16)));
typedef _Float16 f16;
typedef _Float16 f16x2 __attribute__((ext_vector_type(2)));
typedef _Float16 f16x8 __attribute__((ext_vector_type(8)));
typedef unsigned int u32x2 __attribute__((ext_vector_type(2)));
typedef unsigned short u16;
typedef unsigned short u16x4 __attribute__((ext_vector_type(4)));
typedef unsigned int u32;

#define S_LEN 2048
#define NHEAD 16
#define DHEAD 64
#define DMODEL 1024
#define NBATCH 4

__device__ __forceinline__ void gload16(const u16* g, const uint4* l) {
  __builtin_amdgcn_global_load_lds((const __attribute__((address_space(1))) void*)g,
                                   (__attribute__((address_space(3))) void*)l, 16, 0, 0);
}

// exp path: whole chain builtin-visible (exp2f -> cvt_pkrtz -> MFMA). Raw v_exp_f32
// or builtin-exp2 feeding inline-ASM consumers corrupts (r7/r9).
// R3/R5 ROOT CAUSE (found R6): permlane32_swap(x, x) degenerates -> __shfl_xor.
// R7: chained dot2 accumulators cost ~3us latency -> split 4-way.
// R8: pipes are SERIALIZED; only removing total demand helps.
// R9 lesson: K direct global->VGPR in the NATURAL [s][dh] layout scatters each wave
// load across 64 cache lines (64x transactions) AND launch_bounds(256,2) made the
// compiler spill (~10MB scratch in WRITE_SIZE). R10: K stored by qkv in FRAGMENT
// layout -> attn K loads are 64-lane-contiguous 1KB; launch_bounds(256,1).

__device__ __forceinline__ float dot2acc(u32 a, u32 b, float c) {
#if __has_builtin(__builtin_amdgcn_fdot2)
  return __builtin_amdgcn_fdot2(__builtin_bit_cast(f16x2, a), __builtin_bit_cast(f16x2, b), c, false);
#else
  f16x2 pa = __builtin_bit_cast(f16x2, a), pb = __builtin_bit_cast(f16x2, b);
  return c + (float)pa[0] * (float)pb[0] + (float)pa[1] * (float)pb[1];
#endif
}

// ---------------- convert x (f32 -> f16), packed ----------------
__global__ void cvt_x(const float* __restrict__ x, u16* __restrict__ o, int n4) {
  int i = blockIdx.x * blockDim.x + threadIdx.x;
  int st = gridDim.x * blockDim.x;
  for (; i < n4; i += st) {
    float4 v = reinterpret_cast<const float4*>(x)[i];
    uint2 r;
    r.x = __builtin_bit_cast(u32, __builtin_amdgcn_cvt_pkrtz(v.x, v.y));
    r.y = __builtin_bit_cast(u32, __builtin_amdgcn_cvt_pkrtz(v.z, v.w));
    reinterpret_cast<uint2*>(o)[i] = r;
  }
}

// ---------------- transpose W: f32 [K][N] -> f16 [N][K] ----------------
__global__ void trans_w(const float* __restrict__ W, u16* __restrict__ wt) {
  __shared__ float t[32][33];
  int bx = blockIdx.x * 32, by = blockIdx.y * 32;
  int tx = threadIdx.x & 31, ty = threadIdx.x >> 5;  // ty in 0..7
#pragma unroll
  for (int i = 0; i < 32; i += 8)
    t[ty + i][tx] = W[(size_t)(by + ty + i) * DMODEL + bx + tx];
  __syncthreads();
#pragma unroll
  for (int i = 0; i < 32; i += 8)
    wt[(size_t)(bx + ty + i) * DMODEL + by + tx] = __builtin_bit_cast(u16, (f16)t[tx][ty + i]);
}

// ---------------- fused QKV projection GEMM ----------------
// Round-0 envelope (proven): 128x128 tile, BK=32, 4 waves, 48KB LDS, 3 blocks/CU,
// grid (64,24)=1536 blocks -> exactly 2 full scheduling rounds.
// 32x32x16 MFMA engine, acc[2][2] f32x16 (64 AGPR), 8 ds_read_b128/iter.
// 3-buf counted-vmcnt pipeline (T4).
// R10: K output written in MFMA-FRAGMENT layout (see attn) -- same store count,
// addresses within 64B lines instead of 128B-strided.
__global__ __launch_bounds__(256) void qkv_gemm(
    const u16* __restrict__ A, const u16* __restrict__ Wt,
    const float* __restrict__ bq, const float* __restrict__ bk, const float* __restrict__ bv,
    const float* __restrict__ mask,
    u16* __restrict__ Qo, u16* __restrict__ Ko, u16* __restrict__ Vo)
{
  __shared__ uint4 As4[3][512];   // [128 rows][4 slots] per buffer
  __shared__ uint4 Bs4[3][512];
  const int tid = threadIdx.x;
  const int lane = tid & 63;
  const int wid = tid >> 6;
  const int l31 = lane & 31, hi = lane >> 5;
  const int m0 = blockIdx.x * 128;
  const int n0 = blockIdx.y * 128;
  const int wr = (wid >> 1) * 64, wc = (wid & 1) * 64;

  f32x16 acc[2][2] = {};

  // glds geometry: wave w stages phys chunks w*64+lane, +256.
  // phys chunk c = row*4 + p; stored data = logical slot l = p ^ ((row>>1)&3).
  const int c0 = wid * 64 + lane, c1 = c0 + 256;
  const int r0 = c0 >> 2, r1 = c1 >> 2;
  const int p4 = lane & 3;
  const int sl0 = p4 ^ ((r0 >> 1) & 3);
  const int sl1 = p4 ^ ((r1 >> 1) & 3);
  const u16* ag0 = A  + (size_t)(m0 + r0) * 1024 + sl0 * 8;
  const u16* ag1 = A  + (size_t)(m0 + r1) * 1024 + sl1 * 8;
  const u16* bg0 = Wt + (size_t)(n0 + r0) * 1024 + sl0 * 8;
  const u16* bg1 = Wt + (size_t)(n0 + r1) * 1024 + sl1 * 8;

  auto stage = [&](int buf, int kt) {
    gload16(ag0 + kt, &As4[buf][wid * 64]);
    gload16(ag1 + kt, &As4[buf][wid * 64 + 256]);
    gload16(bg0 + kt, &Bs4[buf][wid * 64]);
    gload16(bg1 + kt, &Bs4[buf][wid * 64 + 256]);
  };

  // iteration-invariant LDS read offsets (u16 units)
  int aoff[2][2], boff[2][2];
#pragma unroll
  for (int mi = 0; mi < 2; mi++) {
    int r = wr + mi * 32 + l31;
#pragma unroll
    for (int ks = 0; ks < 2; ks++)
      aoff[mi][ks] = r * 32 + (((ks * 2 + hi) ^ ((r >> 1) & 3)) * 8);
  }
#pragma unroll
  for (int ni = 0; ni < 2; ni++) {
    int r = wc + ni * 32 + l31;
#pragma unroll
    for (int ks = 0; ks < 2; ks++)
      boff[ni][ks] = r * 32 + (((ks * 2 + hi) ^ ((r >> 1) & 3)) * 8);
  }

  stage(0, 0);
  stage(1, 32);
  __syncthreads();              // one-time full drain: buf0+buf1 resident

  const int NT = 1024 / 32;
  for (int it = 0; it < NT; ++it) {
    if (it + 1 < NT) asm volatile("s_waitcnt vmcnt(4)" ::: "memory");
    else             asm volatile("s_waitcnt vmcnt(0)" ::: "memory");
    __builtin_amdgcn_s_barrier();
    __builtin_amdgcn_sched_barrier(0);
    const int cur = it % 3;
    if (it + 2 < NT) stage((it + 2) % 3, (it + 2) * 32);   // stays in flight past barrier

    const u16* As = (const u16*)&As4[cur][0];
    const u16* Bs = (const u16*)&Bs4[cur][0];
    f16x8 af[2][2], bf[2][2];
#pragma unroll
    for (int mi = 0; mi < 2; mi++)
#pragma unroll
      for (int ks = 0; ks < 2; ks++)
        af[mi][ks] = *(const f16x8*)&As[aoff[mi][ks]];
#pragma unroll
    for (int ni = 0; ni < 2; ni++)
#pragma unroll
      for (int ks = 0; ks < 2; ks++)
        bf[ni][ks] = *(const f16x8*)&Bs[boff[ni][ks]];

#pragma unroll
    for (int ks = 0; ks < 2; ks++)
#pragma unroll
      for (int mi = 0; mi < 2; mi++)
#pragma unroll
        for (int ni = 0; ni < 2; ni++)
          acc[mi][ni] = __builtin_amdgcn_mfma_f32_32x32x16_f16(af[mi][ks], bf[ni][ks], acc[mi][ni], 0, 0, 0);
  }

  // ---- epilogue: scatter into Q/K/V layouts ----
  const int sel = n0 >> 10;                    // 0:Q 1:K 2:V
  const float* bias = (sel == 0) ? bq : (sel == 1) ? bk : bv;
  const int nbase = (n0 & 1023) + wc;
  const float QSCALE = 0.18033688011112042f;   // log2(e)/8  (exp2-domain softmax)
#pragma unroll
  for (int mi = 0; mi < 2; mi++)
#pragma unroll
    for (int ni = 0; ni < 2; ni++) {
      const int ncol = nbase + ni * 32 + l31;
      const float bi = bias[ncol];
      const int h = ncol >> 6, dh = ncol & 63;
#pragma unroll
      for (int r4 = 0; r4 < 4; r4++) {
        // C layout (32x32): col = lane&31, row = (reg&3) + 8*(reg>>2) + 4*(lane>>5)
        const int rowb = m0 + wr + mi * 32 + 8 * r4 + 4 * hi;
        const int bb = rowb >> 11, s0 = rowb & 2047;
        const size_t bh = (size_t)(bb * NHEAD + h);
        if (sel == 0) {
#pragma unroll
          for (int j = 0; j < 4; j++)
            Qo[(bh * S_LEN + s0 + j) * DHEAD + dh] =
                __builtin_bit_cast(u16, (f16)((acc[mi][ni][r4 * 4 + j] + bi) * QSCALE));
        } else if (sel == 1) {
          // K in FRAGMENT layout: elem (s,dh) -> it*4096 + (kc*2+half)*512
          //   + hik*256 + l31k*8 + j8  (it=s>>6, half=(s>>5)&1, l31k=s&31,
          //   kc=dh>>4, hik=(dh>>3)&1, j8=dh&7). Makes attn's per-lane K read
          //   64-lane-contiguous (lane = hik*32 + l31k reads at lane*8).
          const int kc_ = dh >> 4, hik = (dh >> 3) & 1, j8 = dh & 7;
          const int it_ = s0 >> 6, hf = (s0 >> 5) & 1;   // s0..s0+3 same half (4-aligned)
          u16* kdst = Ko + bh * ((size_t)S_LEN * DHEAD) + it_ * 4096 +
                      (kc_ * 2 + hf) * 512 + hik * 256 + (s0 & 31) * 8 + j8;
#pragma unroll
          for (int j = 0; j < 4; j++)
            kdst[j * 8] = __builtin_bit_cast(u16, (f16)(acc[mi][ni][r4 * 4 + j] + bi));
        } else {
          const float4 mk = *(const float4*)&mask[bb * S_LEN + s0];   // s0 % 4 == 0
          u16x4 pk;
#pragma unroll
          for (int j = 0; j < 4; j++) {
            float v = acc[mi][ni][r4 * 4 + j] + bi;
            float mj = (j == 0) ? mk.x : (j == 1) ? mk.y : (j == 2) ? mk.z : mk.w;
            if (mj <= 0.f) v = 0.f;            // fold mask into V
            pk[j] = __builtin_bit_cast(u16, (f16)v);
          }
          *(u16x4*)&Vo[(bh * DHEAD + dh) * S_LEN + s0] = pk;  // 4 consecutive s -> 8B store
        }
      }
    }
}

// ---------------- flash attention: swapped-QK^T 32x32 f16, K-in-registers ----------------
// grid 512; 4 waves/block, wave owns q rows q0..q0+63 (two 32-subtiles).
// ROUND 10 (= R9 concept, layout fixed): K is not in LDS. K fragments loaded
// directly global->VGPR from the FRAGMENT-layout Kb (see qkv epilogue): each
// fragment read is 64 lanes x 16B CONTIGUOUS (1KB), L1/L2-resident, prefetched
// one iteration ahead. LDS reads/wave-iter 20 -> 12; K bank conflicts gone;
// QK^T has zero LDS dependency. launch_bounds(256,1): peak live regs ~236 --
// R9's (256,2) made the compiler squeeze to 128 and spill (~10MB scratch).
__global__ __launch_bounds__(256, 1) void attn(
    const u16* __restrict__ Q, const u16* __restrict__ K, const u16* __restrict__ Vt,
    const float* __restrict__ mask, float* __restrict__ out)
{
  __shared__ uint4 Vs4[3][512];                // [d=64][slot=8] skewed (V^T)
  __shared__ __align__(16) u16 MsAll[S_LEN];   // whole mask row as f16 (4KB)
  const int tid = threadIdx.x;
  const int lane = tid & 63, wid = tid >> 6;
  const int l31 = lane & 31, hi = lane >> 5;
  const int sid = blockIdx.x;
  const int qt = (sid >> 3) & 7;
  const int bh = (sid & 7) + 8 * (sid >> 6);
  const int b = bh >> 4, h = bh & 15;
  const size_t base = (size_t)bh * S_LEN * DHEAD;
  const u16* Qp = Q + base;
  const u16* Kp = K + base;                    // fragment layout (see qkv)
  const u16* Vp = Vt + base;                   // [d][s]
  const float* mp = mask + b * S_LEN;
  const int q0 = qt * 256 + wid * 64;

  // Q as B-fragments for the two 32-row subtiles
  f16x8 aqA[4], aqB[4];
#pragma unroll
  for (int kc = 0; kc < 4; kc++) {
    aqA[kc] = *(const f16x8*)&Qp[(size_t)(q0 + l31) * DHEAD + kc * 16 + hi * 8];
    aqB[kc] = *(const f16x8*)&Qp[(size_t)(q0 + 32 + l31) * DHEAD + kc * 16 + hi * 8];
  }

  f32x16 accO0A = {}, accO1A = {};
  f32x16 accO0B = {}, accO1B = {};
  float lAp[4] = {0.f, 0.f, 0.f, 0.f};         // split denominator partials
  float lBp[4] = {0.f, 0.f, 0.f, 0.f};

  // V staging geometry (G21: linear LDS dest, inverse-skewed global source)
  const int cA_ = wid * 128 + lane, cB_ = cA_ + 64;
  const int rk0 = cA_ >> 3, rk1 = cB_ >> 3;
  const int p8 = lane & 7;
  const int cc0 = (p8 - ((rk0 + (rk0 >> 3)) & 7)) & 7;
  const int cc1 = (p8 - ((rk1 + (rk1 >> 3)) & 7)) & 7;
  const u16* vg0 = Vp + (size_t)rk0 * S_LEN + cc0 * 8;
  const u16* vg1 = Vp + (size_t)rk1 * S_LEN + cc1 * 8;

  auto stage = [&](int buf) {
    gload16(vg0, &Vs4[buf][wid * 128]); gload16(vg1, &Vs4[buf][wid * 128 + 64]);
    vg0 += 64; vg1 += 64;
  };

  // LDS read slot table (V's g-loop)
  const int swA = (l31 + (l31 >> 3)) & 7;
  const int swB = (swA + 4) & 7;
  int idxA[4], idxB[4];
#pragma unroll
  for (int kc = 0; kc < 4; kc++) {
    idxA[kc] = l31 * 8 + ((kc * 2 + hi + swA) & 7);
    idxB[kc] = (32 + l31) * 8 + ((kc * 2 + hi + swB) & 7);
  }

  // K fragment base: fragment (kc, half) of tile it at kq + it*4096 + (kc*2+half)*512
  // (u16 units); per-lane offset lane*8 -> 64-lane-contiguous 1KB reads.
  const u16* kq = Kp + lane * 8;

  // one-time mask preload (f32 -> f16, 8 values/thread)
  {
    float4 ml0 = *(const float4*)&mp[tid * 8];
    float4 ml1 = *(const float4*)&mp[tid * 8 + 4];
    uint4 w;
    w.x = __builtin_bit_cast(u32, __builtin_amdgcn_cvt_pkrtz(ml0.x, ml0.y));
    w.y = __builtin_bit_cast(u32, __builtin_amdgcn_cvt_pkrtz(ml0.z, ml0.w));
    w.z = __builtin_bit_cast(u32, __builtin_amdgcn_cvt_pkrtz(ml1.x, ml1.y));
    w.w = __builtin_bit_cast(u32, __builtin_amdgcn_cvt_pkrtz(ml1.z, ml1.w));
    *(uint4*)&MsAll[tid * 8] = w;
  }
  // prologue: V(0), V(1) to LDS; K(0) to registers
  stage(0);
  stage(1);
  f16x8 kr[4][2];
#pragma unroll
  for (int kc = 0; kc < 4; kc++) {
    kr[kc][0] = *(const f16x8*)(kq + kc * 2 * 512);
    kr[kc][1] = *(const f16x8*)(kq + (kc * 2 + 1) * 512);
  }
  __syncthreads();              // full drain: V bufs + MsAll resident, kr landed

  const int NT = S_LEN / 64;
  for (int it = 0; it < NT; ++it) {
    asm volatile("s_waitcnt vmcnt(0)" ::: "memory");   // V(it) + K(it) landed
    __builtin_amdgcn_s_barrier();                      // all waves' stages visible
    __builtin_amdgcn_sched_barrier(0);
    const int cur = it % 3;
    const uint4* vs = &Vs4[cur][0];
    if (it + 2 < NT) stage((it + 2) % 3);              // V prefetch, flies under body

    // K(it+1) prefetch -> krn (consumed next iteration; latency hides under body)
    f16x8 krn[4][2];
    if (it + 1 < NT) {
      const u16* kqn = kq + (it + 1) * 4096;
#pragma unroll
      for (int kc = 0; kc < 4; kc++) {
        krn[kc][0] = *(const f16x8*)(kqn + kc * 2 * 512);
        krn[kc][1] = *(const f16x8*)(kqn + (kc * 2 + 1) * 512);
      }
    }

    // ---- S^T = K Q^T from REGISTERS (no LDS dependency) ----
    f32x16 sA0 = {}, sA1 = {}, sB0 = {}, sB1 = {};
#pragma unroll
    for (int kc = 0; kc < 4; kc++) {
      sA0 = __builtin_amdgcn_mfma_f32_32x32x16_f16(kr[kc][0], aqA[kc], sA0, 0, 0, 0);
      sA1 = __builtin_amdgcn_mfma_f32_32x32x16_f16(kr[kc][1], aqA[kc], sA1, 0, 0, 0);
      sB0 = __builtin_amdgcn_mfma_f32_32x32x16_f16(kr[kc][0], aqB[kc], sB0, 0, 0, 0);
      sB1 = __builtin_amdgcn_mfma_f32_32x32x16_f16(kr[kc][1], aqB[kc], sB1, 0, 0, 0);
    }

    // ---- fused p=exp2(S) -> f16 pack -> permlane -> PV + dot2 denominator ----
#pragma unroll
    for (int g = 0; g < 4; g++) {
      const f32x16& srcA = (g < 2) ? sA0 : sA1;
      const f32x16& srcB = (g < 2) ? sB0 : sB1;
      const int o = (g & 1) * 8;
      u32 wa[4], wb[4];
#pragma unroll
      for (int s = 0; s < 4; s++) {
        wa[s] = __builtin_bit_cast(u32, __builtin_amdgcn_cvt_pkrtz(
                    __builtin_amdgcn_exp2f(srcA[o + 2 * s]),
                    __builtin_amdgcn_exp2f(srcA[o + 2 * s + 1])));
        wb[s] = __builtin_bit_cast(u32, __builtin_amdgcn_cvt_pkrtz(
                    __builtin_amdgcn_exp2f(srcB[o + 2 * s]),
                    __builtin_amdgcn_exp2f(srcB[o + 2 * s + 1])));
      }
      u32x2 rA0 = __builtin_amdgcn_permlane32_swap(wa[0], wa[2], false, false);
      u32x2 rA1 = __builtin_amdgcn_permlane32_swap(wa[1], wa[3], false, false);
      u32x2 rB0 = __builtin_amdgcn_permlane32_swap(wb[0], wb[2], false, false);
      u32x2 rB1 = __builtin_amdgcn_permlane32_swap(wb[1], wb[3], false, false);
      uint4 f4A; f4A.x = rA0[0]; f4A.y = rA1[0]; f4A.z = rA0[1]; f4A.w = rA1[1];
      uint4 f4B; f4B.x = rB0[0]; f4B.y = rB1[0]; f4B.z = rB0[1]; f4B.w = rB1[1];
      f16x8 fA = __builtin_bit_cast(f16x8, f4A);
      f16x8 fB = __builtin_bit_cast(f16x8, f4B);
      f16x8 bv0 = *(const f16x8*)&vs[idxA[g]];
      f16x8 bv1 = *(const f16x8*)&vs[idxB[g]];
      const uint4 bmw = *(const uint4*)&MsAll[it * 64 + g * 16 + hi * 8];
      accO0A = __builtin_amdgcn_mfma_f32_32x32x16_f16(fA, bv0, accO0A, 0, 0, 0);
      accO1A = __builtin_amdgcn_mfma_f32_32x32x16_f16(fA, bv1, accO1A, 0, 0, 0);
      accO0B = __builtin_amdgcn_mfma_f32_32x32x16_f16(fB, bv0, accO0B, 0, 0, 0);
      accO1B = __builtin_amdgcn_mfma_f32_32x32x16_f16(fB, bv1, accO1B, 0, 0, 0);
      lAp[0] = dot2acc(f4A.x, bmw.x, lAp[0]);
      lAp[1] = dot2acc(f4A.y, bmw.y, lAp[1]);
      lAp[2] = dot2acc(f4A.z, bmw.z, lAp[2]);
      lAp[3] = dot2acc(f4A.w, bmw.w, lAp[3]);
      lBp[0] = dot2acc(f4B.x, bmw.x, lBp[0]);
      lBp[1] = dot2acc(f4B.y, bmw.y, lBp[1]);
      lBp[2] = dot2acc(f4B.z, bmw.z, lBp[2]);
      lBp[3] = dot2acc(f4B.w, bmw.w, lBp[3]);
    }

    // rotate K prefetch into place (register rename, no real copy)
#pragma unroll
    for (int kc = 0; kc < 4; kc++) { kr[kc][0] = krn[kc][0]; kr[kc][1] = krn[kc][1]; }
  }

  // ---- epilogue ----
  // merge split partials, then partner t-half via __shfl_xor (NOT permlane32_swap(x,x)).
  float lA = (lAp[0] + lAp[1]) + (lAp[2] + lAp[3]);
  float lB = (lBp[0] + lBp[1]) + (lBp[2] + lBp[3]);
  float lAf = lA + __shfl_xor(lA, 32, 64);
  float lBf = lB + __shfl_xor(lB, 32, 64);
  float invA = (lAf > 0.f) ? 1.f / lAf : 0.f;   // lane holds 1/l for q = l31
  float invB = (lBf > 0.f) ? 1.f / lBf : 0.f;
#pragma unroll
  for (int r = 0; r < 16; r++) {
    int qr = (r & 3) + 8 * (r >> 2) + 4 * hi;
    float iA = __builtin_bit_cast(float,
        (u32)__builtin_amdgcn_ds_bpermute(qr << 2, (int)__builtin_bit_cast(u32, invA)));
    float iB = __builtin_bit_cast(float,
        (u32)__builtin_amdgcn_ds_bpermute(qr << 2, (int)__builtin_bit_cast(u32, invB)));
    float* opA = out + ((size_t)(b * S_LEN + q0 + qr) * DMODEL) + h * DHEAD;
    float* opB = out + ((size_t)(b * S_LEN + q0 + 32 + qr) * DMODEL) + h * DHEAD;
    opA[l31] = accO0A[r] * iA;
    opA[32 + l31] = accO1A[r] * iA;
    opB[l31] = accO0B[r] * iB;
    opB[32 + l31] = accO1B[r] * iB;
  }
}

extern "C" void kernel_launch(void* const* d_in, const int* in_sizes, int n_in,
                              void* d_out, int out_size, void* d_ws, size_t ws_size,
                              hipStream_t stream) {
  const float* x    = (const float*)d_in[0];
  const float* mask = (const float*)d_in[1];
  const float* Wq   = (const float*)d_in[2];
  const float* bq   = (const float*)d_in[3];
  const float* Wk   = (const float*)d_in[4];
  const float* bk   = (const float*)d_in[5];
  const float* Wv   = (const float*)d_in[6];
  const float* bv   = (const float*)d_in[7];
  float* out = (float*)d_out;

  u16* xb = (u16*)d_ws;                         // [8192][1024] f16
  u16* wt = xb + (size_t)8192 * 1024;           // [3072][1024] f16 (W^T, q|k|v)
  u16* Qb = wt + (size_t)3072 * 1024;           // [4][16][2048][64]
  u16* Kb = Qb + (size_t)8388608;               // [4][16] fragment-layout tiles
  u16* Vb = Kb + (size_t)8388608;               // [4][16][64][2048] (mask-zeroed)

  cvt_x<<<2048, 256, 0, stream>>>(x, xb, (8192 * 1024) / 4);
  trans_w<<<dim3(32, 32), 256, 0, stream>>>(Wq, wt);
  trans_w<<<dim3(32, 32), 256, 0, stream>>>(Wk, wt + (size_t)1024 * 1024);
  trans_w<<<dim3(32, 32), 256, 0, stream>>>(Wv, wt + (size_t)2 * 1024 * 1024);
  qkv_gemm<<<dim3(64, 24), 256, 0, stream>>>(xb, wt, bq, bk, bv, mask, Qb, Kb, Vb);
  attn<<<512, 256, 0, stream>>>(Qb, Kb, Vb, mask, out);
}

// Round 11
// 188.265 us; speedup vs baseline: 1.1309x; 1.0448x over previous
//
#include <hip/hip_runtime.h>

typedef float f32x4 __attribute__((ext_vector_type(4)));
typedef float f32x16 __attribute__((ext_vector_type(16)));
typedef _Float16 f16;
typedef _Float16 f16x2 __attribute__((ext_vector_type(2)));
typedef _Float16 f16x8 __attribute__((ext_vector_type(8)));
typedef unsigned int u32x2 __attribute__((ext_vector_type(2)));
typedef unsigned short u16;
typedef unsigned short u16x4 __attribute__((ext_vector_type(4)));
typedef unsigned int u32;

#define S_LEN 2048
#define NHEAD 16
#define DHEAD 64
#define DMODEL 1024
#define NBATCH 4

__device__ __forceinline__ void gload16(const u16* g, const uint4* l) {
  __builtin_amdgcn_global_load_lds((const __attribute__((address_space(1))) void*)g,
                                   (__attribute__((address_space(3))) void*)l, 16, 0, 0);
}

// exp path: whole chain builtin-visible (exp2f -> cvt_pkrtz -> MFMA). Raw v_exp_f32
// or builtin-exp2 feeding inline-ASM consumers corrupts (r7/r9).
// R3/R5 ROOT CAUSE (found R6): permlane32_swap(x, x) degenerates -> __shfl_xor.
// R7: chained dot2 accumulators cost ~3us latency -> split 4-way.
// R8: pipes are SERIALIZED; only removing total demand helps.
// R9: K-direct in [s][dh] layout = 64x uncoalesced + complex addressing spilled.
// R10: fragment-layout K fixed coalescing/spill (FETCH 24.8MB, WRITE clean, 132 VGPR)
// but launch_bounds(256,1) PINNED occupancy to 1 block/CU (Occ 10.6%) -> 116us.
// R11: launch_bounds(256,2) -- reg cap 256 >> the 132 this code needs; 2 blocks/CU.

__device__ __forceinline__ float dot2acc(u32 a, u32 b, float c) {
#if __has_builtin(__builtin_amdgcn_fdot2)
  return __builtin_amdgcn_fdot2(__builtin_bit_cast(f16x2, a), __builtin_bit_cast(f16x2, b), c, false);
#else
  f16x2 pa = __builtin_bit_cast(f16x2, a), pb = __builtin_bit_cast(f16x2, b);
  return c + (float)pa[0] * (float)pb[0] + (float)pa[1] * (float)pb[1];
#endif
}

// ---------------- convert x (f32 -> f16), packed ----------------
__global__ void cvt_x(const float* __restrict__ x, u16* __restrict__ o, int n4) {
  int i = blockIdx.x * blockDim.x + threadIdx.x;
  int st = gridDim.x * blockDim.x;
  for (; i < n4; i += st) {
    float4 v = reinterpret_cast<const float4*>(x)[i];
    uint2 r;
    r.x = __builtin_bit_cast(u32, __builtin_amdgcn_cvt_pkrtz(v.x, v.y));
    r.y = __builtin_bit_cast(u32, __builtin_amdgcn_cvt_pkrtz(v.z, v.w));
    reinterpret_cast<uint2*>(o)[i] = r;
  }
}

// ---------------- transpose W: f32 [K][N] -> f16 [N][K] ----------------
__global__ void trans_w(const float* __restrict__ W, u16* __restrict__ wt) {
  __shared__ float t[32][33];
  int bx = blockIdx.x * 32, by = blockIdx.y * 32;
  int tx = threadIdx.x & 31, ty = threadIdx.x >> 5;  // ty in 0..7
#pragma unroll
  for (int i = 0; i < 32; i += 8)
    t[ty + i][tx] = W[(size_t)(by + ty + i) * DMODEL + bx + tx];
  __syncthreads();
#pragma unroll
  for (int i = 0; i < 32; i += 8)
    wt[(size_t)(bx + ty + i) * DMODEL + by + tx] = __builtin_bit_cast(u16, (f16)t[tx][ty + i]);
}

// ---------------- fused QKV projection GEMM ----------------
// Round-0 envelope (proven): 128x128 tile, BK=32, 4 waves, 48KB LDS, 3 blocks/CU,
// grid (64,24)=1536 blocks -> exactly 2 full scheduling rounds.
// 32x32x16 MFMA engine, acc[2][2] f32x16 (64 AGPR), 8 ds_read_b128/iter.
// 3-buf counted-vmcnt pipeline (T4).
// K output written in MFMA-FRAGMENT layout (see attn) -- same store count,
// addresses within 64B lines instead of 128B-strided.
__global__ __launch_bounds__(256) void qkv_gemm(
    const u16* __restrict__ A, const u16* __restrict__ Wt,
    const float* __restrict__ bq, const float* __restrict__ bk, const float* __restrict__ bv,
    const float* __restrict__ mask,
    u16* __restrict__ Qo, u16* __restrict__ Ko, u16* __restrict__ Vo)
{
  __shared__ uint4 As4[3][512];   // [128 rows][4 slots] per buffer
  __shared__ uint4 Bs4[3][512];
  const int tid = threadIdx.x;
  const int lane = tid & 63;
  const int wid = tid >> 6;
  const int l31 = lane & 31, hi = lane >> 5;
  const int m0 = blockIdx.x * 128;
  const int n0 = blockIdx.y * 128;
  const int wr = (wid >> 1) * 64, wc = (wid & 1) * 64;

  f32x16 acc[2][2] = {};

  // glds geometry: wave w stages phys chunks w*64+lane, +256.
  // phys chunk c = row*4 + p; stored data = logical slot l = p ^ ((row>>1)&3).
  const int c0 = wid * 64 + lane, c1 = c0 + 256;
  const int r0 = c0 >> 2, r1 = c1 >> 2;
  const int p4 = lane & 3;
  const int sl0 = p4 ^ ((r0 >> 1) & 3);
  const int sl1 = p4 ^ ((r1 >> 1) & 3);
  const u16* ag0 = A  + (size_t)(m0 + r0) * 1024 + sl0 * 8;
  const u16* ag1 = A  + (size_t)(m0 + r1) * 1024 + sl1 * 8;
  const u16* bg0 = Wt + (size_t)(n0 + r0) * 1024 + sl0 * 8;
  const u16* bg1 = Wt + (size_t)(n0 + r1) * 1024 + sl1 * 8;

  auto stage = [&](int buf, int kt) {
    gload16(ag0 + kt, &As4[buf][wid * 64]);
    gload16(ag1 + kt, &As4[buf][wid * 64 + 256]);
    gload16(bg0 + kt, &Bs4[buf][wid * 64]);
    gload16(bg1 + kt, &Bs4[buf][wid * 64 + 256]);
  };

  // iteration-invariant LDS read offsets (u16 units)
  int aoff[2][2], boff[2][2];
#pragma unroll
  for (int mi = 0; mi < 2; mi++) {
    int r = wr + mi * 32 + l31;
#pragma unroll
    for (int ks = 0; ks < 2; ks++)
      aoff[mi][ks] = r * 32 + (((ks * 2 + hi) ^ ((r >> 1) & 3)) * 8);
  }
#pragma unroll
  for (int ni = 0; ni < 2; ni++) {
    int r = wc + ni * 32 + l31;
#pragma unroll
    for (int ks = 0; ks < 2; ks++)
      boff[ni][ks] = r * 32 + (((ks * 2 + hi) ^ ((r >> 1) & 3)) * 8);
  }

  stage(0, 0);
  stage(1, 32);
  __syncthreads();              // one-time full drain: buf0+buf1 resident

  const int NT = 1024 / 32;
  for (int it = 0; it < NT; ++it) {
    if (it + 1 < NT) asm volatile("s_waitcnt vmcnt(4)" ::: "memory");
    else             asm volatile("s_waitcnt vmcnt(0)" ::: "memory");
    __builtin_amdgcn_s_barrier();
    __builtin_amdgcn_sched_barrier(0);
    const int cur = it % 3;
    if (it + 2 < NT) stage((it + 2) % 3, (it + 2) * 32);   // stays in flight past barrier

    const u16* As = (const u16*)&As4[cur][0];
    const u16* Bs = (const u16*)&Bs4[cur][0];
    f16x8 af[2][2], bf[2][2];
#pragma unroll
    for (int mi = 0; mi < 2; mi++)
#pragma unroll
      for (int ks = 0; ks < 2; ks++)
        af[mi][ks] = *(const f16x8*)&As[aoff[mi][ks]];
#pragma unroll
    for (int ni = 0; ni < 2; ni++)
#pragma unroll
      for (int ks = 0; ks < 2; ks++)
        bf[ni][ks] = *(const f16x8*)&Bs[boff[ni][ks]];

#pragma unroll
    for (int ks = 0; ks < 2; ks++)
#pragma unroll
      for (int mi = 0; mi < 2; mi++)
#pragma unroll
        for (int ni = 0; ni < 2; ni++)
          acc[mi][ni] = __builtin_amdgcn_mfma_f32_32x32x16_f16(af[mi][ks], bf[ni][ks], acc[mi][ni], 0, 0, 0);
  }

  // ---- epilogue: scatter into Q/K/V layouts ----
  const int sel = n0 >> 10;                    // 0:Q 1:K 2:V
  const float* bias = (sel == 0) ? bq : (sel == 1) ? bk : bv;
  const int nbase = (n0 & 1023) + wc;
  const float QSCALE = 0.18033688011112042f;   // log2(e)/8  (exp2-domain softmax)
#pragma unroll
  for (int mi = 0; mi < 2; mi++)
#pragma unroll
    for (int ni = 0; ni < 2; ni++) {
      const int ncol = nbase + ni * 32 + l31;
      const float bi = bias[ncol];
      const int h = ncol >> 6, dh = ncol & 63;
#pragma unroll
      for (int r4 = 0; r4 < 4; r4++) {
        // C layout (32x32): col = lane&31, row = (reg&3) + 8*(reg>>2) + 4*(lane>>5)
        const int rowb = m0 + wr + mi * 32 + 8 * r4 + 4 * hi;
        const int bb = rowb >> 11, s0 = rowb & 2047;
        const size_t bh = (size_t)(bb * NHEAD + h);
        if (sel == 0) {
#pragma unroll
          for (int j = 0; j < 4; j++)
            Qo[(bh * S_LEN + s0 + j) * DHEAD + dh] =
                __builtin_bit_cast(u16, (f16)((acc[mi][ni][r4 * 4 + j] + bi) * QSCALE));
        } else if (sel == 1) {
          // K in FRAGMENT layout: elem (s,dh) -> it*4096 + (kc*2+half)*512
          //   + hik*256 + l31k*8 + j8  (it=s>>6, half=(s>>5)&1, l31k=s&31,
          //   kc=dh>>4, hik=(dh>>3)&1, j8=dh&7). Makes attn's per-lane K read
          //   64-lane-contiguous (lane = hik*32 + l31k reads at lane*8).
          const int kc_ = dh >> 4, hik = (dh >> 3) & 1, j8 = dh & 7;
          const int it_ = s0 >> 6, hf = (s0 >> 5) & 1;   // s0..s0+3 same half (4-aligned)
          u16* kdst = Ko + bh * ((size_t)S_LEN * DHEAD) + it_ * 4096 +
                      (kc_ * 2 + hf) * 512 + hik * 256 + (s0 & 31) * 8 + j8;
#pragma unroll
          for (int j = 0; j < 4; j++)
            kdst[j * 8] = __builtin_bit_cast(u16, (f16)(acc[mi][ni][r4 * 4 + j] + bi));
        } else {
          const float4 mk = *(const float4*)&mask[bb * S_LEN + s0];   // s0 % 4 == 0
          u16x4 pk;
#pragma unroll
          for (int j = 0; j < 4; j++) {
            float v = acc[mi][ni][r4 * 4 + j] + bi;
            float mj = (j == 0) ? mk.x : (j == 1) ? mk.y : (j == 2) ? mk.z : mk.w;
            if (mj <= 0.f) v = 0.f;            // fold mask into V
            pk[j] = __builtin_bit_cast(u16, (f16)v);
          }
          *(u16x4*)&Vo[(bh * DHEAD + dh) * S_LEN + s0] = pk;  // 4 consecutive s -> 8B store
        }
      }
    }
}

// ---------------- flash attention: swapped-QK^T 32x32 f16, K-in-registers ----------------
// grid 512; 4 waves/block, wave owns q rows q0..q0+63 (two 32-subtiles).
// K is not in LDS: fragments loaded directly global->VGPR from the FRAGMENT-layout
// Kb (see qkv epilogue): each fragment read is 64 lanes x 16B CONTIGUOUS (1KB),
// L1/L2-resident, prefetched one iteration ahead. LDS reads/wave-iter 20 -> 12;
// K bank conflicts gone; QK^T has zero LDS dependency.
// R11: launch_bounds(256,2) -- (256,1) pinned occupancy to 1 block/CU (R10);
// this code needs only 132 VGPR so the 256-reg cap is never binding.
__global__ __launch_bounds__(256, 2) void attn(
    const u16* __restrict__ Q, const u16* __restrict__ K, const u16* __restrict__ Vt,
    const float* __restrict__ mask, float* __restrict__ out)
{
  __shared__ uint4 Vs4[3][512];                // [d=64][slot=8] skewed (V^T)
  __shared__ __align__(16) u16 MsAll[S_LEN];   // whole mask row as f16 (4KB)
  const int tid = threadIdx.x;
  const int lane = tid & 63, wid = tid >> 6;
  const int l31 = lane & 31, hi = lane >> 5;
  const int sid = blockIdx.x;
  const int qt = (sid >> 3) & 7;
  const int bh = (sid & 7) + 8 * (sid >> 6);
  const int b = bh >> 4, h = bh & 15;
  const size_t base = (size_t)bh * S_LEN * DHEAD;
  const u16* Qp = Q + base;
  const u16* Kp = K + base;                    // fragment layout (see qkv)
  const u16* Vp = Vt + base;                   // [d][s]
  const float* mp = mask + b * S_LEN;
  const int q0 = qt * 256 + wid * 64;

  // Q as B-fragments for the two 32-row subtiles
  f16x8 aqA[4], aqB[4];
#pragma unroll
  for (int kc = 0; kc < 4; kc++) {
    aqA[kc] = *(const f16x8*)&Qp[(size_t)(q0 + l31) * DHEAD + kc * 16 + hi * 8];
    aqB[kc] = *(const f16x8*)&Qp[(size_t)(q0 + 32 + l31) * DHEAD + kc * 16 + hi * 8];
  }

  f32x16 accO0A = {}, accO1A = {};
  f32x16 accO0B = {}, accO1B = {};
  float lAp[4] = {0.f, 0.f, 0.f, 0.f};         // split denominator partials
  float lBp[4] = {0.f, 0.f, 0.f, 0.f};

  // V staging geometry (G21: linear LDS dest, inverse-skewed global source)
  const int cA_ = wid * 128 + lane, cB_ = cA_ + 64;
  const int rk0 = cA_ >> 3, rk1 = cB_ >> 3;
  const int p8 = lane & 7;
  const int cc0 = (p8 - ((rk0 + (rk0 >> 3)) & 7)) & 7;
  const int cc1 = (p8 - ((rk1 + (rk1 >> 3)) & 7)) & 7;
  const u16* vg0 = Vp + (size_t)rk0 * S_LEN + cc0 * 8;
  const u16* vg1 = Vp + (size_t)rk1 * S_LEN + cc1 * 8;

  auto stage = [&](int buf) {
    gload16(vg0, &Vs4[buf][wid * 128]); gload16(vg1, &Vs4[buf][wid * 128 + 64]);
    vg0 += 64; vg1 += 64;
  };

  // LDS read slot table (V's g-loop)
  const int swA = (l31 + (l31 >> 3)) & 7;
  const int swB = (swA + 4) & 7;
  int idxA[4], idxB[4];
#pragma unroll
  for (int kc = 0; kc < 4; kc++) {
    idxA[kc] = l31 * 8 + ((kc * 2 + hi + swA) & 7);
    idxB[kc] = (32 + l31) * 8 + ((kc * 2 + hi + swB) & 7);
  }

  // K fragment base: fragment (kc, half) of tile it at kq + it*4096 + (kc*2+half)*512
  // (u16 units); per-lane offset lane*8 -> 64-lane-contiguous 1KB reads.
  const u16* kq = Kp + lane * 8;

  // one-time mask preload (f32 -> f16, 8 values/thread)
  {
    float4 ml0 = *(const float4*)&mp[tid * 8];
    float4 ml1 = *(const float4*)&mp[tid * 8 + 4];
    uint4 w;
    w.x = __builtin_bit_cast(u32, __builtin_amdgcn_cvt_pkrtz(ml0.x, ml0.y));
    w.y = __builtin_bit_cast(u32, __builtin_amdgcn_cvt_pkrtz(ml0.z, ml0.w));
    w.z = __builtin_bit_cast(u32, __builtin_amdgcn_cvt_pkrtz(ml1.x, ml1.y));
    w.w = __builtin_bit_cast(u32, __builtin_amdgcn_cvt_pkrtz(ml1.z, ml1.w));
    *(uint4*)&MsAll[tid * 8] = w;
  }
  // prologue: V(0), V(1) to LDS; K(0) to registers
  stage(0);
  stage(1);
  f16x8 kr[4][2];
#pragma unroll
  for (int kc = 0; kc < 4; kc++) {
    kr[kc][0] = *(const f16x8*)(kq + kc * 2 * 512);
    kr[kc][1] = *(const f16x8*)(kq + (kc * 2 + 1) * 512);
  }
  __syncthreads();              // full drain: V bufs + MsAll resident, kr landed

  const int NT = S_LEN / 64;
  for (int it = 0; it < NT; ++it) {
    asm volatile("s_waitcnt vmcnt(0)" ::: "memory");   // V(it) + K(it) landed
    __builtin_amdgcn_s_barrier();                      // all waves' stages visible
    __builtin_amdgcn_sched_barrier(0);
    const int cur = it % 3;
    const uint4* vs = &Vs4[cur][0];
    if (it + 2 < NT) stage((it + 2) % 3);              // V prefetch, flies under body

    // K(it+1) prefetch -> krn (consumed next iteration; latency hides under body)
    f16x8 krn[4][2];
    if (it + 1 < NT) {
      const u16* kqn = kq + (it + 1) * 4096;
#pragma unroll
      for (int kc = 0; kc < 4; kc++) {
        krn[kc][0] = *(const f16x8*)(kqn + kc * 2 * 512);
        krn[kc][1] = *(const f16x8*)(kqn + (kc * 2 + 1) * 512);
      }
    }

    // ---- S^T = K Q^T from REGISTERS (no LDS dependency) ----
    f32x16 sA0 = {}, sA1 = {}, sB0 = {}, sB1 = {};
#pragma unroll
    for (int kc = 0; kc < 4; kc++) {
      sA0 = __builtin_amdgcn_mfma_f32_32x32x16_f16(kr[kc][0], aqA[kc], sA0, 0, 0, 0);
      sA1 = __builtin_amdgcn_mfma_f32_32x32x16_f16(kr[kc][1], aqA[kc], sA1, 0, 0, 0);
      sB0 = __builtin_amdgcn_mfma_f32_32x32x16_f16(kr[kc][0], aqB[kc], sB0, 0, 0, 0);
      sB1 = __builtin_amdgcn_mfma_f32_32x32x16_f16(kr[kc][1], aqB[kc], sB1, 0, 0, 0);
    }

    // ---- fused p=exp2(S) -> f16 pack -> permlane -> PV + dot2 denominator ----
#pragma unroll
    for (int g = 0; g < 4; g++) {
      const f32x16& srcA = (g < 2) ? sA0 : sA1;
      const f32x16& srcB = (g < 2) ? sB0 : sB1;
      const int o = (g & 1) * 8;
      u32 wa[4], wb[4];
#pragma unroll
      for (int s = 0; s < 4; s++) {
        wa[s] = __builtin_bit_cast(u32, __builtin_amdgcn_cvt_pkrtz(
                    __builtin_amdgcn_exp2f(srcA[o + 2 * s]),
                    __builtin_amdgcn_exp2f(srcA[o + 2 * s + 1])));
        wb[s] = __builtin_bit_cast(u32, __builtin_amdgcn_cvt_pkrtz(
                    __builtin_amdgcn_exp2f(srcB[o + 2 * s]),
                    __builtin_amdgcn_exp2f(srcB[o + 2 * s + 1])));
      }
      u32x2 rA0 = __builtin_amdgcn_permlane32_swap(wa[0], wa[2], false, false);
      u32x2 rA1 = __builtin_amdgcn_permlane32_swap(wa[1], wa[3], false, false);
      u32x2 rB0 = __builtin_amdgcn_permlane32_swap(wb[0], wb[2], false, false);
      u32x2 rB1 = __builtin_amdgcn_permlane32_swap(wb[1], wb[3], false, false);
      uint4 f4A; f4A.x = rA0[0]; f4A.y = rA1[0]; f4A.z = rA0[1]; f4A.w = rA1[1];
      uint4 f4B; f4B.x = rB0[0]; f4B.y = rB1[0]; f4B.z = rB0[1]; f4B.w = rB1[1];
      f16x8 fA = __builtin_bit_cast(f16x8, f4A);
      f16x8 fB = __builtin_bit_cast(f16x8, f4B);
      f16x8 bv0 = *(const f16x8*)&vs[idxA[g]];
      f16x8 bv1 = *(const f16x8*)&vs[idxB[g]];
      const uint4 bmw = *(const uint4*)&MsAll[it * 64 + g * 16 + hi * 8];
      accO0A = __builtin_amdgcn_mfma_f32_32x32x16_f16(fA, bv0, accO0A, 0, 0, 0);
      accO1A = __builtin_amdgcn_mfma_f32_32x32x16_f16(fA, bv1, accO1A, 0, 0, 0);
      accO0B = __builtin_amdgcn_mfma_f32_32x32x16_f16(fB, bv0, accO0B, 0, 0, 0);
      accO1B = __builtin_amdgcn_mfma_f32_32x32x16_f16(fB, bv1, accO1B, 0, 0, 0);
      lAp[0] = dot2acc(f4A.x, bmw.x, lAp[0]);
      lAp[1] = dot2acc(f4A.y, bmw.y, lAp[1]);
      lAp[2] = dot2acc(f4A.z, bmw.z, lAp[2]);
      lAp[3] = dot2acc(f4A.w, bmw.w, lAp[3]);
      lBp[0] = dot2acc(f4B.x, bmw.x, lBp[0]);
      lBp[1] = dot2acc(f4B.y, bmw.y, lBp[1]);
      lBp[2] = dot2acc(f4B.z, bmw.z, lBp[2]);
      lBp[3] = dot2acc(f4B.w, bmw.w, lBp[3]);
    }

    // rotate K prefetch into place (register rename, no real copy)
#pragma unroll
    for (int kc = 0; kc < 4; kc++) { kr[kc][0] = krn[kc][0]; kr[kc][1] = krn[kc][1]; }
  }

  // ---- epilogue ----
  // merge split partials, then partner t-half via __shfl_xor (NOT permlane32_swap(x,x)).
  float lA = (lAp[0] + lAp[1]) + (lAp[2] + lAp[3]);
  float lB = (lBp[0] + lBp[1]) + (lBp[2] + lBp[3]);
  float lAf = lA + __shfl_xor(lA, 32, 64);
  float lBf = lB + __shfl_xor(lB, 32, 64);
  float invA = (lAf > 0.f) ? 1.f / lAf : 0.f;   // lane holds 1/l for q = l31
  float invB = (lBf > 0.f) ? 1.f / lBf : 0.f;
#pragma unroll
  for (int r = 0; r < 16; r++) {
    int qr = (r & 3) + 8 * (r >> 2) + 4 * hi;
    float iA = __builtin_bit_cast(float,
        (u32)__builtin_amdgcn_ds_bpermute(qr << 2, (int)__builtin_bit_cast(u32, invA)));
    float iB = __builtin_bit_cast(float,
        (u32)__builtin_amdgcn_ds_bpermute(qr << 2, (int)__builtin_bit_cast(u32, invB)));
    float* opA = out + ((size_t)(b * S_LEN + q0 + qr) * DMODEL) + h * DHEAD;
    float* opB = out + ((size_t)(b * S_LEN + q0 + 32 + qr) * DMODEL) + h * DHEAD;
    opA[l31] = accO0A[r] * iA;
    opA[32 + l31] = accO1A[r] * iA;
    opB[l31] = accO0B[r] * iB;
    opB[32 + l31] = accO1B[r] * iB;
  }
}

extern "C" void kernel_launch(void* const* d_in, const int* in_sizes, int n_in,
                              void* d_out, int out_size, void* d_ws, size_t ws_size,
                              hipStream_t stream) {
  const float* x    = (const float*)d_in[0];
  const float* mask = (const float*)d_in[1];
  const float* Wq   = (const float*)d_in[2];
  const float* bq   = (const float*)d_in[3];
  const float* Wk   = (const float*)d_in[4];
  const float* bk   = (const float*)d_in[5];
  const float* Wv   = (const float*)d_in[6];
  const float* bv   = (const float*)d_in[7];
  float* out = (float*)d_out;

  u16* xb = (u16*)d_ws;                         // [8192][1024] f16
  u16* wt = xb + (size_t)8192 * 1024;           // [3072][1024] f16 (W^T, q|k|v)
  u16* Qb = wt + (size_t)3072 * 1024;           // [4][16][2048][64]
  u16* Kb = Qb + (size_t)8388608;               // [4][16] fragment-layout tiles
  u16* Vb = Kb + (size_t)8388608;               // [4][16][64][2048] (mask-zeroed)

  cvt_x<<<2048, 256, 0, stream>>>(x, xb, (8192 * 1024) / 4);
  trans_w<<<dim3(32, 32), 256, 0, stream>>>(Wq, wt);
  trans_w<<<dim3(32, 32), 256, 0, stream>>>(Wk, wt + (size_t)1024 * 1024);
  trans_w<<<dim3(32, 32), 256, 0, stream>>>(Wv, wt + (size_t)2 * 1024 * 1024);
  qkv_gemm<<<dim3(64, 24), 256, 0, stream>>>(xb, wt, bq, bk, bv, mask, Qb, Kb, Vb);
  attn<<<512, 256, 0, stream>>>(Qb, Kb, Vb, mask, out);
}

// Round 12
// 164.769 us; speedup vs baseline: 1.2922x; 1.1426x over previous
//
#include <hip/hip_runtime.h>

typedef float f32x4 __attribute__((ext_vector_type(4)));
typedef float f32x16 __attribute__((ext_vector_type(16)));
typedef _Float16 f16;
typedef _Float16 f16x2 __attribute__((ext_vector_type(2)));
typedef _Float16 f16x8 __attribute__((ext_vector_type(8)));
typedef unsigned int u32x2 __attribute__((ext_vector_type(2)));
typedef unsigned short u16;
typedef unsigned short u16x4 __attribute__((ext_vector_type(4)));
typedef unsigned int u32;

#define S_LEN 2048
#define NHEAD 16
#define DHEAD 64
#define DMODEL 1024
#define NBATCH 4

__device__ __forceinline__ void gload16(const u16* g, const uint4* l) {
  __builtin_amdgcn_global_load_lds((const __attribute__((address_space(1))) void*)g,
                                   (__attribute__((address_space(3))) void*)l, 16, 0, 0);
}

// exp path: whole chain builtin-visible (exp2f -> cvt_pkrtz -> MFMA). Raw v_exp_f32
// or builtin-exp2 feeding inline-ASM consumers corrupts (r7/r9).
// R3/R5 ROOT CAUSE (found R6): permlane32_swap(x, x) degenerates -> __shfl_xor.
// R7: chained dot2 accumulators cost ~3us latency -> split 4-way.
// R8: pipes are SERIALIZED; only removing total demand helps. attn plateau ~83us
// across 6 structures (R2/R6/R7/R8 ~83-86; R4 16-wave ~85; R9-11 K-direct 110-136).
// R9-R11 lesson (closed): K-in-registers kills cross-wave sharing (each wave loads
// the whole 8KB K tile; VMEM instr/wave-iter 4->10) -- K stays in LDS. Also:
// launch_bounds 2nd arg 2 => hipcc squeezes to 128 VGPR and spills if need >128;
// 2nd arg 1 => pins occupancy to 1 block/CU. R8's (256,2) at 128 VGPR exactly fits.
// R12: revert attn to R8-exact; qkv grid transposed for L2 locality; cvt_x+trans_w
// merged into one prep kernel (3 fewer launch gaps).

__device__ __forceinline__ float dot2acc(u32 a, u32 b, float c) {
#if __has_builtin(__builtin_amdgcn_fdot2)
  return __builtin_amdgcn_fdot2(__builtin_bit_cast(f16x2, a), __builtin_bit_cast(f16x2, b), c, false);
#else
  f16x2 pa = __builtin_bit_cast(f16x2, a), pb = __builtin_bit_cast(f16x2, b);
  return c + (float)pa[0] * (float)pb[0] + (float)pa[1] * (float)pb[1];
#endif
}

// ---------------- merged preprocessing: cvt_x (f32->f16) + 3x trans_w ----------------
// blocks [0,2048): x convert (grid-stride over 2M float4s).
// blocks [2048,5120): W transpose; 1024 blocks per W (Wq|Wk|Wv).
__global__ __launch_bounds__(256) void prep(
    const float* __restrict__ x, u16* __restrict__ xb,
    const float* __restrict__ Wq, const float* __restrict__ Wk,
    const float* __restrict__ Wv, u16* __restrict__ wt)
{
  __shared__ float t[32][33];
  const int id = blockIdx.x;
  if (id < 2048) {
    const int n4 = (8192 * 1024) / 4;
    int i = id * 256 + threadIdx.x;
    const int st = 2048 * 256;
    for (; i < n4; i += st) {
      float4 v = reinterpret_cast<const float4*>(x)[i];
      uint2 r;
      r.x = __builtin_bit_cast(u32, __builtin_amdgcn_cvt_pkrtz(v.x, v.y));
      r.y = __builtin_bit_cast(u32, __builtin_amdgcn_cvt_pkrtz(v.z, v.w));
      reinterpret_cast<uint2*>(xb)[i] = r;
    }
  } else {
    const int tw = id - 2048;
    const int w = tw >> 10, rem = tw & 1023;
    const float* W = (w == 0) ? Wq : (w == 1) ? Wk : Wv;
    u16* o = wt + (size_t)w * 1024 * 1024;
    const int bx = (rem & 31) * 32, by = (rem >> 5) * 32;
    const int tx = threadIdx.x & 31, ty = threadIdx.x >> 5;  // ty in 0..7
#pragma unroll
    for (int i = 0; i < 32; i += 8)
      t[ty + i][tx] = W[(size_t)(by + ty + i) * DMODEL + bx + tx];
    __syncthreads();
#pragma unroll
    for (int i = 0; i < 32; i += 8)
      o[(size_t)(bx + ty + i) * DMODEL + by + tx] = __builtin_bit_cast(u16, (f16)t[tx][ty + i]);
  }
}

// ---------------- fused QKV projection GEMM ----------------
// Proven envelope: 128x128 tile, BK=32, 4 waves, 48KB LDS, 3 blocks/CU,
// grid (24,64)=1536 blocks -> 2 full scheduling rounds. 32x32x16 MFMA engine,
// acc[2][2] f32x16, 8 ds_read_b128/iter. 3-buf counted-vmcnt pipeline (T4).
// R12: grid transposed (n0 = x fast, m0 = y) -- consecutive blocks share one A
// panel (256KB) + the whole 6MB Wt (L2-resident) instead of streaming 16MB of A.
__global__ __launch_bounds__(256) void qkv_gemm(
    const u16* __restrict__ A, const u16* __restrict__ Wt,
    const float* __restrict__ bq, const float* __restrict__ bk, const float* __restrict__ bv,
    const float* __restrict__ mask,
    u16* __restrict__ Qo, u16* __restrict__ Ko, u16* __restrict__ Vo)
{
  __shared__ uint4 As4[3][512];   // [128 rows][4 slots] per buffer
  __shared__ uint4 Bs4[3][512];
  const int tid = threadIdx.x;
  const int lane = tid & 63;
  const int wid = tid >> 6;
  const int l31 = lane & 31, hi = lane >> 5;
  const int m0 = blockIdx.y * 128;
  const int n0 = blockIdx.x * 128;
  const int wr = (wid >> 1) * 64, wc = (wid & 1) * 64;

  f32x16 acc[2][2] = {};

  // glds geometry: wave w stages phys chunks w*64+lane, +256.
  // phys chunk c = row*4 + p; stored data = logical slot l = p ^ ((row>>1)&3).
  const int c0 = wid * 64 + lane, c1 = c0 + 256;
  const int r0 = c0 >> 2, r1 = c1 >> 2;
  const int p4 = lane & 3;
  const int sl0 = p4 ^ ((r0 >> 1) & 3);
  const int sl1 = p4 ^ ((r1 >> 1) & 3);
  const u16* ag0 = A  + (size_t)(m0 + r0) * 1024 + sl0 * 8;
  const u16* ag1 = A  + (size_t)(m0 + r1) * 1024 + sl1 * 8;
  const u16* bg0 = Wt + (size_t)(n0 + r0) * 1024 + sl0 * 8;
  const u16* bg1 = Wt + (size_t)(n0 + r1) * 1024 + sl1 * 8;

  auto stage = [&](int buf, int kt) {
    gload16(ag0 + kt, &As4[buf][wid * 64]);
    gload16(ag1 + kt, &As4[buf][wid * 64 + 256]);
    gload16(bg0 + kt, &Bs4[buf][wid * 64]);
    gload16(bg1 + kt, &Bs4[buf][wid * 64 + 256]);
  };

  // iteration-invariant LDS read offsets (u16 units)
  int aoff[2][2], boff[2][2];
#pragma unroll
  for (int mi = 0; mi < 2; mi++) {
    int r = wr + mi * 32 + l31;
#pragma unroll
    for (int ks = 0; ks < 2; ks++)
      aoff[mi][ks] = r * 32 + (((ks * 2 + hi) ^ ((r >> 1) & 3)) * 8);
  }
#pragma unroll
  for (int ni = 0; ni < 2; ni++) {
    int r = wc + ni * 32 + l31;
#pragma unroll
    for (int ks = 0; ks < 2; ks++)
      boff[ni][ks] = r * 32 + (((ks * 2 + hi) ^ ((r >> 1) & 3)) * 8);
  }

  stage(0, 0);
  stage(1, 32);
  __syncthreads();              // one-time full drain: buf0+buf1 resident

  const int NT = 1024 / 32;
  for (int it = 0; it < NT; ++it) {
    if (it + 1 < NT) asm volatile("s_waitcnt vmcnt(4)" ::: "memory");
    else             asm volatile("s_waitcnt vmcnt(0)" ::: "memory");
    __builtin_amdgcn_s_barrier();
    __builtin_amdgcn_sched_barrier(0);
    const int cur = it % 3;
    if (it + 2 < NT) stage((it + 2) % 3, (it + 2) * 32);   // stays in flight past barrier

    const u16* As = (const u16*)&As4[cur][0];
    const u16* Bs = (const u16*)&Bs4[cur][0];
    f16x8 af[2][2], bf[2][2];
#pragma unroll
    for (int mi = 0; mi < 2; mi++)
#pragma unroll
      for (int ks = 0; ks < 2; ks++)
        af[mi][ks] = *(const f16x8*)&As[aoff[mi][ks]];
#pragma unroll
    for (int ni = 0; ni < 2; ni++)
#pragma unroll
      for (int ks = 0; ks < 2; ks++)
        bf[ni][ks] = *(const f16x8*)&Bs[boff[ni][ks]];

#pragma unroll
    for (int ks = 0; ks < 2; ks++)
#pragma unroll
      for (int mi = 0; mi < 2; mi++)
#pragma unroll
        for (int ni = 0; ni < 2; ni++)
          acc[mi][ni] = __builtin_amdgcn_mfma_f32_32x32x16_f16(af[mi][ks], bf[ni][ks], acc[mi][ni], 0, 0, 0);
  }

  // ---- epilogue: scatter into Q/K/V layouts (natural K layout -- R8-proven) ----
  const int sel = n0 >> 10;                    // 0:Q 1:K 2:V
  const float* bias = (sel == 0) ? bq : (sel == 1) ? bk : bv;
  const int nbase = (n0 & 1023) + wc;
  const float QSCALE = 0.18033688011112042f;   // log2(e)/8  (exp2-domain softmax)
#pragma unroll
  for (int mi = 0; mi < 2; mi++)
#pragma unroll
    for (int ni = 0; ni < 2; ni++) {
      const int ncol = nbase + ni * 32 + l31;
      const float bi = bias[ncol];
      const int h = ncol >> 6, dh = ncol & 63;
#pragma unroll
      for (int r4 = 0; r4 < 4; r4++) {
        // C layout (32x32): col = lane&31, row = (reg&3) + 8*(reg>>2) + 4*(lane>>5)
        const int rowb = m0 + wr + mi * 32 + 8 * r4 + 4 * hi;
        const int bb = rowb >> 11, s0 = rowb & 2047;
        const size_t bh = (size_t)(bb * NHEAD + h);
        if (sel == 0) {
#pragma unroll
          for (int j = 0; j < 4; j++)
            Qo[(bh * S_LEN + s0 + j) * DHEAD + dh] =
                __builtin_bit_cast(u16, (f16)((acc[mi][ni][r4 * 4 + j] + bi) * QSCALE));
        } else if (sel == 1) {
#pragma unroll
          for (int j = 0; j < 4; j++)
            Ko[(bh * S_LEN + s0 + j) * DHEAD + dh] =
                __builtin_bit_cast(u16, (f16)(acc[mi][ni][r4 * 4 + j] + bi));
        } else {
          const float4 mk = *(const float4*)&mask[bb * S_LEN + s0];   // s0 % 4 == 0
          u16x4 pk;
#pragma unroll
          for (int j = 0; j < 4; j++) {
            float v = acc[mi][ni][r4 * 4 + j] + bi;
            float mj = (j == 0) ? mk.x : (j == 1) ? mk.y : (j == 2) ? mk.z : mk.w;
            if (mj <= 0.f) v = 0.f;            // fold mask into V
            pk[j] = __builtin_bit_cast(u16, (f16)v);
          }
          *(u16x4*)&Vo[(bh * DHEAD + dh) * S_LEN + s0] = pk;  // 4 consecutive s -> 8B store
        }
      }
    }
}

// ---------------- flash attention: swapped-QK^T 32x32 f16, software-pipelined ----------------
// R8-EXACT (proven 82.9us): grid 512; 4 waves/block, wave owns q rows q0..q0+63.
// QK^T(it+1) (pure MFMA, K from buf it+1 -- resident under the 3-buf discipline)
// co-scheduled with exp/pack/PV/dot2(it). Gate = vmcnt(0). dot2 denominator with
// 4-way split accumulators. No setprio in the loop.
__global__ __launch_bounds__(256, 2) void attn(
    const u16* __restrict__ Q, const u16* __restrict__ K, const u16* __restrict__ Vt,
    const float* __restrict__ mask, float* __restrict__ out)
{
  __shared__ uint4 Ks4[3][512];                // [t=64][slot=8] skewed 16B chunks
  __shared__ uint4 Vs4[3][512];                // [d=64][slot=8] skewed (V^T)
  __shared__ __align__(16) u16 MsAll[S_LEN];   // whole mask row as f16 (4KB)
  const int tid = threadIdx.x;
  const int lane = tid & 63, wid = tid >> 6;
  const int l31 = lane & 31, hi = lane >> 5;
  const int sid = blockIdx.x;
  const int qt = (sid >> 3) & 7;
  const int bh = (sid & 7) + 8 * (sid >> 6);
  const int b = bh >> 4, h = bh & 15;
  const size_t base = (size_t)bh * S_LEN * DHEAD;
  const u16* Qp = Q + base;
  const u16* Kp = K + base;
  const u16* Vp = Vt + base;                   // [d][s]
  const float* mp = mask + b * S_LEN;
  const int q0 = qt * 256 + wid * 64;

  // Q as B-fragments for the two 32-row subtiles
  f16x8 aqA[4], aqB[4];
#pragma unroll
  for (int kc = 0; kc < 4; kc++) {
    aqA[kc] = *(const f16x8*)&Qp[(size_t)(q0 + l31) * DHEAD + kc * 16 + hi * 8];
    aqB[kc] = *(const f16x8*)&Qp[(size_t)(q0 + 32 + l31) * DHEAD + kc * 16 + hi * 8];
  }

  f32x16 accO0A = {}, accO1A = {};
  f32x16 accO0B = {}, accO1B = {};
  float lAp[4] = {0.f, 0.f, 0.f, 0.f};         // split denominator partials
  float lBp[4] = {0.f, 0.f, 0.f, 0.f};

  // staging geometry (G21: linear LDS dest, inverse-skewed global source)
  const int cA_ = wid * 128 + lane, cB_ = cA_ + 64;
  const int rk0 = cA_ >> 3, rk1 = cB_ >> 3;
  const int p8 = lane & 7;
  const int cc0 = (p8 - ((rk0 + (rk0 >> 3)) & 7)) & 7;
  const int cc1 = (p8 - ((rk1 + (rk1 >> 3)) & 7)) & 7;
  const u16* kg0 = Kp + (size_t)rk0 * DHEAD + cc0 * 8;
  const u16* kg1 = Kp + (size_t)rk1 * DHEAD + cc1 * 8;
  const u16* vg0 = Vp + (size_t)rk0 * S_LEN + cc0 * 8;
  const u16* vg1 = Vp + (size_t)rk1 * S_LEN + cc1 * 8;

  auto stage = [&](int buf) {
    gload16(kg0, &Ks4[buf][wid * 128]); gload16(kg1, &Ks4[buf][wid * 128 + 64]);
    gload16(vg0, &Vs4[buf][wid * 128]); gload16(vg1, &Vs4[buf][wid * 128 + 64]);
    kg0 += 64 * DHEAD; kg1 += 64 * DHEAD; vg0 += 64; vg1 += 64;
  };

  // LDS read slot table (shared by K's kc-loop and V's g-loop)
  const int swA = (l31 + (l31 >> 3)) & 7;
  const int swB = (swA + 4) & 7;
  int idxA[4], idxB[4];
#pragma unroll
  for (int kc = 0; kc < 4; kc++) {
    idxA[kc] = l31 * 8 + ((kc * 2 + hi + swA) & 7);
    idxB[kc] = (32 + l31) * 8 + ((kc * 2 + hi + swB) & 7);
  }

  // one-time mask preload (f32 -> f16, 8 values/thread)
  {
    float4 ml0 = *(const float4*)&mp[tid * 8];
    float4 ml1 = *(const float4*)&mp[tid * 8 + 4];
    uint4 w;
    w.x = __builtin_bit_cast(u32, __builtin_amdgcn_cvt_pkrtz(ml0.x, ml0.y));
    w.y = __builtin_bit_cast(u32, __builtin_amdgcn_cvt_pkrtz(ml0.z, ml0.w));
    w.z = __builtin_bit_cast(u32, __builtin_amdgcn_cvt_pkrtz(ml1.x, ml1.y));
    w.w = __builtin_bit_cast(u32, __builtin_amdgcn_cvt_pkrtz(ml1.z, ml1.w));
    *(uint4*)&MsAll[tid * 8] = w;
  }
  stage(0);
  stage(1);
  __syncthreads();              // one-time full drain: buf0+buf1+MsAll resident

  // pipeline state: S^T of the CURRENT iteration (computed one iteration ahead)
  f32x16 pA0 = {}, pA1 = {}, pB0 = {}, pB1 = {};

  auto qkt = [&](const uint4* ks, f32x16& A0, f32x16& A1, f32x16& B0, f32x16& B1) {
#pragma unroll
    for (int kc = 0; kc < 4; kc++) {
      f16x8 k0 = *(const f16x8*)&ks[idxA[kc]];
      f16x8 k1 = *(const f16x8*)&ks[idxB[kc]];
      A0 = __builtin_amdgcn_mfma_f32_32x32x16_f16(k0, aqA[kc], A0, 0, 0, 0);
      A1 = __builtin_amdgcn_mfma_f32_32x32x16_f16(k1, aqA[kc], A1, 0, 0, 0);
      B0 = __builtin_amdgcn_mfma_f32_32x32x16_f16(k0, aqB[kc], B0, 0, 0, 0);
      B1 = __builtin_amdgcn_mfma_f32_32x32x16_f16(k1, aqB[kc], B1, 0, 0, 0);
    }
  };

  // exp/pack/permlane/PV/dot2 on the p-state (iteration it), V+mask of tile it
  auto phaseB = [&](const uint4* vs, int it) {
#pragma unroll
    for (int g = 0; g < 4; g++) {
      const f32x16& srcA = (g < 2) ? pA0 : pA1;
      const f32x16& srcB = (g < 2) ? pB0 : pB1;
      const int o = (g & 1) * 8;
      u32 wa[4], wb[4];
#pragma unroll
      for (int s = 0; s < 4; s++) {
        wa[s] = __builtin_bit_cast(u32, __builtin_amdgcn_cvt_pkrtz(
                    __builtin_amdgcn_exp2f(srcA[o + 2 * s]),
                    __builtin_amdgcn_exp2f(srcA[o + 2 * s + 1])));
        wb[s] = __builtin_bit_cast(u32, __builtin_amdgcn_cvt_pkrtz(
                    __builtin_amdgcn_exp2f(srcB[o + 2 * s]),
                    __builtin_amdgcn_exp2f(srcB[o + 2 * s + 1])));
      }
      u32x2 rA0 = __builtin_amdgcn_permlane32_swap(wa[0], wa[2], false, false);
      u32x2 rA1 = __builtin_amdgcn_permlane32_swap(wa[1], wa[3], false, false);
      u32x2 rB0 = __builtin_amdgcn_permlane32_swap(wb[0], wb[2], false, false);
      u32x2 rB1 = __builtin_amdgcn_permlane32_swap(wb[1], wb[3], false, false);
      uint4 f4A; f4A.x = rA0[0]; f4A.y = rA1[0]; f4A.z = rA0[1]; f4A.w = rA1[1];
      uint4 f4B; f4B.x = rB0[0]; f4B.y = rB1[0]; f4B.z = rB0[1]; f4B.w = rB1[1];
      f16x8 fA = __builtin_bit_cast(f16x8, f4A);
      f16x8 fB = __builtin_bit_cast(f16x8, f4B);
      f16x8 bv0 = *(const f16x8*)&vs[idxA[g]];
      f16x8 bv1 = *(const f16x8*)&vs[idxB[g]];
      const uint4 bmw = *(const uint4*)&MsAll[it * 64 + g * 16 + hi * 8];
      accO0A = __builtin_amdgcn_mfma_f32_32x32x16_f16(fA, bv0, accO0A, 0, 0, 0);
      accO1A = __builtin_amdgcn_mfma_f32_32x32x16_f16(fA, bv1, accO1A, 0, 0, 0);
      accO0B = __builtin_amdgcn_mfma_f32_32x32x16_f16(fB, bv0, accO0B, 0, 0, 0);
      accO1B = __builtin_amdgcn_mfma_f32_32x32x16_f16(fB, bv1, accO1B, 0, 0, 0);
      lAp[0] = dot2acc(f4A.x, bmw.x, lAp[0]);
      lAp[1] = dot2acc(f4A.y, bmw.y, lAp[1]);
      lAp[2] = dot2acc(f4A.z, bmw.z, lAp[2]);
      lAp[3] = dot2acc(f4A.w, bmw.w, lAp[3]);
      lBp[0] = dot2acc(f4B.x, bmw.x, lBp[0]);
      lBp[1] = dot2acc(f4B.y, bmw.y, lBp[1]);
      lBp[2] = dot2acc(f4B.z, bmw.z, lBp[2]);
      lBp[3] = dot2acc(f4B.w, bmw.w, lBp[3]);
    }
  };

  // prologue: S(0) from buf0 (resident after syncthreads)
  qkt(&Ks4[0][0], pA0, pA1, pB0, pB1);

  const int NT = S_LEN / 64;
  for (int it = 0; it < NT - 1; ++it) {
    asm volatile("s_waitcnt vmcnt(0)" ::: "memory");   // all stages landed (buf it, it+1 resident)
    __builtin_amdgcn_s_barrier();                      // all waves done with buf it-1's data
    __builtin_amdgcn_sched_barrier(0);
    const int cur = it % 3, nxt = (it + 1) % 3;
    if (it + 2 < NT) stage((it + 2) % 3);              // overwrites buf it-1; flies under body
    // pipelined body: QK^T(it+1) [MFMA] interleaved with exp/PV/dot2(it) [VALU+TRANS+MFMA]
    f32x16 nA0 = {}, nA1 = {}, nB0 = {}, nB1 = {};
    qkt(&Ks4[nxt][0], nA0, nA1, nB0, nB1);
    phaseB(&Vs4[cur][0], it);
    pA0 = nA0; pA1 = nA1; pB0 = nB0; pB1 = nB1;
  }
  // peeled final iteration: no stage, no barrier needed (reads-only, buffer resident)
  phaseB(&Vs4[(NT - 1) % 3][0], NT - 1);

  // ---- epilogue ----
  // merge split partials, then partner t-half via __shfl_xor (NOT permlane32_swap(x,x)).
  float lA = (lAp[0] + lAp[1]) + (lAp[2] + lAp[3]);
  float lB = (lBp[0] + lBp[1]) + (lBp[2] + lBp[3]);
  float lAf = lA + __shfl_xor(lA, 32, 64);
  float lBf = lB + __shfl_xor(lB, 32, 64);
  float invA = (lAf > 0.f) ? 1.f / lAf : 0.f;   // lane holds 1/l for q = l31
  float invB = (lBf > 0.f) ? 1.f / lBf : 0.f;
#pragma unroll
  for (int r = 0; r < 16; r++) {
    int qr = (r & 3) + 8 * (r >> 2) + 4 * hi;
    float iA = __builtin_bit_cast(float,
        (u32)__builtin_amdgcn_ds_bpermute(qr << 2, (int)__builtin_bit_cast(u32, invA)));
    float iB = __builtin_bit_cast(float,
        (u32)__builtin_amdgcn_ds_bpermute(qr << 2, (int)__builtin_bit_cast(u32, invB)));
    float* opA = out + ((size_t)(b * S_LEN + q0 + qr) * DMODEL) + h * DHEAD;
    float* opB = out + ((size_t)(b * S_LEN + q0 + 32 + qr) * DMODEL) + h * DHEAD;
    opA[l31] = accO0A[r] * iA;
    opA[32 + l31] = accO1A[r] * iA;
    opB[l31] = accO0B[r] * iB;
    opB[32 + l31] = accO1B[r] * iB;
  }
}

extern "C" void kernel_launch(void* const* d_in, const int* in_sizes, int n_in,
                              void* d_out, int out_size, void* d_ws, size_t ws_size,
                              hipStream_t stream) {
  const float* x    = (const float*)d_in[0];
  const float* mask = (const float*)d_in[1];
  const float* Wq   = (const float*)d_in[2];
  const float* bq   = (const float*)d_in[3];
  const float* Wk   = (const float*)d_in[4];
  const float* bk   = (const float*)d_in[5];
  const float* Wv   = (const float*)d_in[6];
  const float* bv   = (const float*)d_in[7];
  float* out = (float*)d_out;

  u16* xb = (u16*)d_ws;                         // [8192][1024] f16
  u16* wt = xb + (size_t)8192 * 1024;           // [3072][1024] f16 (W^T, q|k|v)
  u16* Qb = wt + (size_t)3072 * 1024;           // [4][16][2048][64]
  u16* Kb = Qb + (size_t)8388608;               // [4][16][2048][64]
  u16* Vb = Kb + (size_t)8388608;               // [4][16][64][2048] (mask-zeroed)

  prep<<<5120, 256, 0, stream>>>(x, xb, Wq, Wk, Wv, wt);
  qkv_gemm<<<dim3(24, 64), 256, 0, stream>>>(xb, wt, bq, bk, bv, mask, Qb, Kb, Vb);
  attn<<<512, 256, 0, stream>>>(Qb, Kb, Vb, mask, out);
}

// Round 13
// 162.756 us; speedup vs baseline: 1.3082x; 1.0124x over previous
//
#include <hip/hip_runtime.h>

typedef float f32x4 __attribute__((ext_vector_type(4)));
typedef float f32x16 __attribute__((ext_vector_type(16)));
typedef _Float16 f16;
typedef _Float16 f16x2 __attribute__((ext_vector_type(2)));
typedef _Float16 f16x8 __attribute__((ext_vector_type(8)));
typedef unsigned int u32x2 __attribute__((ext_vector_type(2)));
typedef unsigned short u16;
typedef unsigned short u16x4 __attribute__((ext_vector_type(4)));
typedef unsigned int u32;

#define S_LEN 2048
#define NHEAD 16
#define DHEAD 64
#define DMODEL 1024
#define NBATCH 4

__device__ __forceinline__ void gload16(const u16* g, const uint4* l) {
  __builtin_amdgcn_global_load_lds((const __attribute__((address_space(1))) void*)g,
                                   (__attribute__((address_space(3))) void*)l, 16, 0, 0);
}

// exp path: whole chain builtin-visible (exp2f -> cvt_pkrtz -> MFMA). Raw v_exp_f32
// or builtin-exp2 feeding inline-ASM consumers corrupts (r7/r9).
// R3/R5 ROOT CAUSE (found R6): permlane32_swap(x, x) degenerates -> __shfl_xor.
// R7: chained dot2 accumulators cost ~3us latency -> split 4-way.
// R8: pipes are SERIALIZED; only removing total demand helps. attn plateau ~83us
// across 6 structures. R9-R11 (closed): K stays in LDS (K-in-reg kills cross-wave
// sharing). launch_bounds 2nd arg: 2 => squeeze-to-128+spill if need >128; 1 =>
// occupancy pinned to 1 block/CU. R8's (256,2) at 128 VGPR exactly fits.
// R12 lesson: qkv grid transpose (n-fastest) DOUBLED FETCH (41->72MB): per-XCD L2
// is 4MB PRIVATE, not 32MB aggregate -- 6MB Wt doesn't fit one XCD slice; m-fastest
// order keeps the active Wt slice resident and streams A once. R13: reverted.

__device__ __forceinline__ float dot2acc(u32 a, u32 b, float c) {
#if __has_builtin(__builtin_amdgcn_fdot2)
  return __builtin_amdgcn_fdot2(__builtin_bit_cast(f16x2, a), __builtin_bit_cast(f16x2, b), c, false);
#else
  f16x2 pa = __builtin_bit_cast(f16x2, a), pb = __builtin_bit_cast(f16x2, b);
  return c + (float)pa[0] * (float)pb[0] + (float)pa[1] * (float)pb[1];
#endif
}

// ---------------- merged preprocessing: cvt_x (f32->f16) + 3x trans_w ----------------
// blocks [0,2048): x convert (grid-stride over 2M float4s).
// blocks [2048,5120): W transpose; 1024 blocks per W (Wq|Wk|Wv).
__global__ __launch_bounds__(256) void prep(
    const float* __restrict__ x, u16* __restrict__ xb,
    const float* __restrict__ Wq, const float* __restrict__ Wk,
    const float* __restrict__ Wv, u16* __restrict__ wt)
{
  __shared__ float t[32][33];
  const int id = blockIdx.x;
  if (id < 2048) {
    const int n4 = (8192 * 1024) / 4;
    int i = id * 256 + threadIdx.x;
    const int st = 2048 * 256;
    for (; i < n4; i += st) {
      float4 v = reinterpret_cast<const float4*>(x)[i];
      uint2 r;
      r.x = __builtin_bit_cast(u32, __builtin_amdgcn_cvt_pkrtz(v.x, v.y));
      r.y = __builtin_bit_cast(u32, __builtin_amdgcn_cvt_pkrtz(v.z, v.w));
      reinterpret_cast<uint2*>(xb)[i] = r;
    }
  } else {
    const int tw = id - 2048;
    const int w = tw >> 10, rem = tw & 1023;
    const float* W = (w == 0) ? Wq : (w == 1) ? Wk : Wv;
    u16* o = wt + (size_t)w * 1024 * 1024;
    const int bx = (rem & 31) * 32, by = (rem >> 5) * 32;
    const int tx = threadIdx.x & 31, ty = threadIdx.x >> 5;  // ty in 0..7
#pragma unroll
    for (int i = 0; i < 32; i += 8)
      t[ty + i][tx] = W[(size_t)(by + ty + i) * DMODEL + bx + tx];
    __syncthreads();
#pragma unroll
    for (int i = 0; i < 32; i += 8)
      o[(size_t)(bx + ty + i) * DMODEL + by + tx] = __builtin_bit_cast(u16, (f16)t[tx][ty + i]);
  }
}

// ---------------- fused QKV projection GEMM ----------------
// Proven envelope (R2-R11, ~41MB FETCH): 128x128 tile, BK=32, 4 waves, 48KB LDS,
// 3 blocks/CU, grid (64,24) m-FASTEST -> 2 full scheduling rounds. 32x32x16 MFMA
// engine, acc[2][2] f32x16, 8 ds_read_b128/iter. 3-buf counted-vmcnt pipeline (T4).
__global__ __launch_bounds__(256) void qkv_gemm(
    const u16* __restrict__ A, const u16* __restrict__ Wt,
    const float* __restrict__ bq, const float* __restrict__ bk, const float* __restrict__ bv,
    const float* __restrict__ mask,
    u16* __restrict__ Qo, u16* __restrict__ Ko, u16* __restrict__ Vo)
{
  __shared__ uint4 As4[3][512];   // [128 rows][4 slots] per buffer
  __shared__ uint4 Bs4[3][512];
  const int tid = threadIdx.x;
  const int lane = tid & 63;
  const int wid = tid >> 6;
  const int l31 = lane & 31, hi = lane >> 5;
  const int m0 = blockIdx.x * 128;
  const int n0 = blockIdx.y * 128;
  const int wr = (wid >> 1) * 64, wc = (wid & 1) * 64;

  f32x16 acc[2][2] = {};

  // glds geometry: wave w stages phys chunks w*64+lane, +256.
  // phys chunk c = row*4 + p; stored data = logical slot l = p ^ ((row>>1)&3).
  const int c0 = wid * 64 + lane, c1 = c0 + 256;
  const int r0 = c0 >> 2, r1 = c1 >> 2;
  const int p4 = lane & 3;
  const int sl0 = p4 ^ ((r0 >> 1) & 3);
  const int sl1 = p4 ^ ((r1 >> 1) & 3);
  const u16* ag0 = A  + (size_t)(m0 + r0) * 1024 + sl0 * 8;
  const u16* ag1 = A  + (size_t)(m0 + r1) * 1024 + sl1 * 8;
  const u16* bg0 = Wt + (size_t)(n0 + r0) * 1024 + sl0 * 8;
  const u16* bg1 = Wt + (size_t)(n0 + r1) * 1024 + sl1 * 8;

  auto stage = [&](int buf, int kt) {
    gload16(ag0 + kt, &As4[buf][wid * 64]);
    gload16(ag1 + kt, &As4[buf][wid * 64 + 256]);
    gload16(bg0 + kt, &Bs4[buf][wid * 64]);
    gload16(bg1 + kt, &Bs4[buf][wid * 64 + 256]);
  };

  // iteration-invariant LDS read offsets (u16 units)
  int aoff[2][2], boff[2][2];
#pragma unroll
  for (int mi = 0; mi < 2; mi++) {
    int r = wr + mi * 32 + l31;
#pragma unroll
    for (int ks = 0; ks < 2; ks++)
      aoff[mi][ks] = r * 32 + (((ks * 2 + hi) ^ ((r >> 1) & 3)) * 8);
  }
#pragma unroll
  for (int ni = 0; ni < 2; ni++) {
    int r = wc + ni * 32 + l31;
#pragma unroll
    for (int ks = 0; ks < 2; ks++)
      boff[ni][ks] = r * 32 + (((ks * 2 + hi) ^ ((r >> 1) & 3)) * 8);
  }

  stage(0, 0);
  stage(1, 32);
  __syncthreads();              // one-time full drain: buf0+buf1 resident

  const int NT = 1024 / 32;
  for (int it = 0; it < NT; ++it) {
    if (it + 1 < NT) asm volatile("s_waitcnt vmcnt(4)" ::: "memory");
    else             asm volatile("s_waitcnt vmcnt(0)" ::: "memory");
    __builtin_amdgcn_s_barrier();
    __builtin_amdgcn_sched_barrier(0);
    const int cur = it % 3;
    if (it + 2 < NT) stage((it + 2) % 3, (it + 2) * 32);   // stays in flight past barrier

    const u16* As = (const u16*)&As4[cur][0];
    const u16* Bs = (const u16*)&Bs4[cur][0];
    f16x8 af[2][2], bf[2][2];
#pragma unroll
    for (int mi = 0; mi < 2; mi++)
#pragma unroll
      for (int ks = 0; ks < 2; ks++)
        af[mi][ks] = *(const f16x8*)&As[aoff[mi][ks]];
#pragma unroll
    for (int ni = 0; ni < 2; ni++)
#pragma unroll
      for (int ks = 0; ks < 2; ks++)
        bf[ni][ks] = *(const f16x8*)&Bs[boff[ni][ks]];

#pragma unroll
    for (int ks = 0; ks < 2; ks++)
#pragma unroll
      for (int mi = 0; mi < 2; mi++)
#pragma unroll
        for (int ni = 0; ni < 2; ni++)
          acc[mi][ni] = __builtin_amdgcn_mfma_f32_32x32x16_f16(af[mi][ks], bf[ni][ks], acc[mi][ni], 0, 0, 0);
  }

  // ---- epilogue: scatter into Q/K/V layouts ----
  const int sel = n0 >> 10;                    // 0:Q 1:K 2:V
  const float* bias = (sel == 0) ? bq : (sel == 1) ? bk : bv;
  const int nbase = (n0 & 1023) + wc;
  const float QSCALE = 0.18033688011112042f;   // log2(e)/8  (exp2-domain softmax)
#pragma unroll
  for (int mi = 0; mi < 2; mi++)
#pragma unroll
    for (int ni = 0; ni < 2; ni++) {
      const int ncol = nbase + ni * 32 + l31;
      const float bi = bias[ncol];
      const int h = ncol >> 6, dh = ncol & 63;
#pragma unroll
      for (int r4 = 0; r4 < 4; r4++) {
        // C layout (32x32): col = lane&31, row = (reg&3) + 8*(reg>>2) + 4*(lane>>5)
        const int rowb = m0 + wr + mi * 32 + 8 * r4 + 4 * hi;
        const int bb = rowb >> 11, s0 = rowb & 2047;
        const size_t bh = (size_t)(bb * NHEAD + h);
        if (sel == 0) {
#pragma unroll
          for (int j = 0; j < 4; j++)
            Qo[(bh * S_LEN + s0 + j) * DHEAD + dh] =
                __builtin_bit_cast(u16, (f16)((acc[mi][ni][r4 * 4 + j] + bi) * QSCALE));
        } else if (sel == 1) {
#pragma unroll
          for (int j = 0; j < 4; j++)
            Ko[(bh * S_LEN + s0 + j) * DHEAD + dh] =
                __builtin_bit_cast(u16, (f16)(acc[mi][ni][r4 * 4 + j] + bi));
        } else {
          const float4 mk = *(const float4*)&mask[bb * S_LEN + s0];   // s0 % 4 == 0
          u16x4 pk;
#pragma unroll
          for (int j = 0; j < 4; j++) {
            float v = acc[mi][ni][r4 * 4 + j] + bi;
            float mj = (j == 0) ? mk.x : (j == 1) ? mk.y : (j == 2) ? mk.z : mk.w;
            if (mj <= 0.f) v = 0.f;            // fold mask into V
            pk[j] = __builtin_bit_cast(u16, (f16)v);
          }
          *(u16x4*)&Vo[(bh * DHEAD + dh) * S_LEN + s0] = pk;  // 4 consecutive s -> 8B store
        }
      }
    }
}

// ---------------- flash attention: swapped-QK^T 32x32 f16, software-pipelined ----------------
// R8-EXACT (proven 82.9us): grid 512; 4 waves/block, wave owns q rows q0..q0+63.
// QK^T(it+1) (pure MFMA, K from buf it+1 -- resident under the 3-buf discipline)
// co-scheduled with exp/pack/PV/dot2(it). Gate = vmcnt(0). dot2 denominator with
// 4-way split accumulators. No setprio in the loop.
__global__ __launch_bounds__(256, 2) void attn(
    const u16* __restrict__ Q, const u16* __restrict__ K, const u16* __restrict__ Vt,
    const float* __restrict__ mask, float* __restrict__ out)
{
  __shared__ uint4 Ks4[3][512];                // [t=64][slot=8] skewed 16B chunks
  __shared__ uint4 Vs4[3][512];                // [d=64][slot=8] skewed (V^T)
  __shared__ __align__(16) u16 MsAll[S_LEN];   // whole mask row as f16 (4KB)
  const int tid = threadIdx.x;
  const int lane = tid & 63, wid = tid >> 6;
  const int l31 = lane & 31, hi = lane >> 5;
  const int sid = blockIdx.x;
  const int qt = (sid >> 3) & 7;
  const int bh = (sid & 7) + 8 * (sid >> 6);
  const int b = bh >> 4, h = bh & 15;
  const size_t base = (size_t)bh * S_LEN * DHEAD;
  const u16* Qp = Q + base;
  const u16* Kp = K + base;
  const u16* Vp = Vt + base;                   // [d][s]
  const float* mp = mask + b * S_LEN;
  const int q0 = qt * 256 + wid * 64;

  // Q as B-fragments for the two 32-row subtiles
  f16x8 aqA[4], aqB[4];
#pragma unroll
  for (int kc = 0; kc < 4; kc++) {
    aqA[kc] = *(const f16x8*)&Qp[(size_t)(q0 + l31) * DHEAD + kc * 16 + hi * 8];
    aqB[kc] = *(const f16x8*)&Qp[(size_t)(q0 + 32 + l31) * DHEAD + kc * 16 + hi * 8];
  }

  f32x16 accO0A = {}, accO1A = {};
  f32x16 accO0B = {}, accO1B = {};
  float lAp[4] = {0.f, 0.f, 0.f, 0.f};         // split denominator partials
  float lBp[4] = {0.f, 0.f, 0.f, 0.f};

  // staging geometry (G21: linear LDS dest, inverse-skewed global source)
  const int cA_ = wid * 128 + lane, cB_ = cA_ + 64;
  const int rk0 = cA_ >> 3, rk1 = cB_ >> 3;
  const int p8 = lane & 7;
  const int cc0 = (p8 - ((rk0 + (rk0 >> 3)) & 7)) & 7;
  const int cc1 = (p8 - ((rk1 + (rk1 >> 3)) & 7)) & 7;
  const u16* kg0 = Kp + (size_t)rk0 * DHEAD + cc0 * 8;
  const u16* kg1 = Kp + (size_t)rk1 * DHEAD + cc1 * 8;
  const u16* vg0 = Vp + (size_t)rk0 * S_LEN + cc0 * 8;
  const u16* vg1 = Vp + (size_t)rk1 * S_LEN + cc1 * 8;

  auto stage = [&](int buf) {
    gload16(kg0, &Ks4[buf][wid * 128]); gload16(kg1, &Ks4[buf][wid * 128 + 64]);
    gload16(vg0, &Vs4[buf][wid * 128]); gload16(vg1, &Vs4[buf][wid * 128 + 64]);
    kg0 += 64 * DHEAD; kg1 += 64 * DHEAD; vg0 += 64; vg1 += 64;
  };

  // LDS read slot table (shared by K's kc-loop and V's g-loop)
  const int swA = (l31 + (l31 >> 3)) & 7;
  const int swB = (swA + 4) & 7;
  int idxA[4], idxB[4];
#pragma unroll
  for (int kc = 0; kc < 4; kc++) {
    idxA[kc] = l31 * 8 + ((kc * 2 + hi + swA) & 7);
    idxB[kc] = (32 + l31) * 8 + ((kc * 2 + hi + swB) & 7);
  }

  // one-time mask preload (f32 -> f16, 8 values/thread)
  {
    float4 ml0 = *(const float4*)&mp[tid * 8];
    float4 ml1 = *(const float4*)&mp[tid * 8 + 4];
    uint4 w;
    w.x = __builtin_bit_cast(u32, __builtin_amdgcn_cvt_pkrtz(ml0.x, ml0.y));
    w.y = __builtin_bit_cast(u32, __builtin_amdgcn_cvt_pkrtz(ml0.z, ml0.w));
    w.z = __builtin_bit_cast(u32, __builtin_amdgcn_cvt_pkrtz(ml1.x, ml1.y));
    w.w = __builtin_bit_cast(u32, __builtin_amdgcn_cvt_pkrtz(ml1.z, ml1.w));
    *(uint4*)&MsAll[tid * 8] = w;
  }
  stage(0);
  stage(1);
  __syncthreads();              // one-time full drain: buf0+buf1+MsAll resident

  // pipeline state: S^T of the CURRENT iteration (computed one iteration ahead)
  f32x16 pA0 = {}, pA1 = {}, pB0 = {}, pB1 = {};

  auto qkt = [&](const uint4* ks, f32x16& A0, f32x16& A1, f32x16& B0, f32x16& B1) {
#pragma unroll
    for (int kc = 0; kc < 4; kc++) {
      f16x8 k0 = *(const f16x8*)&ks[idxA[kc]];
      f16x8 k1 = *(const f16x8*)&ks[idxB[kc]];
      A0 = __builtin_amdgcn_mfma_f32_32x32x16_f16(k0, aqA[kc], A0, 0, 0, 0);
      A1 = __builtin_amdgcn_mfma_f32_32x32x16_f16(k1, aqA[kc], A1, 0, 0, 0);
      B0 = __builtin_amdgcn_mfma_f32_32x32x16_f16(k0, aqB[kc], B0, 0, 0, 0);
      B1 = __builtin_amdgcn_mfma_f32_32x32x16_f16(k1, aqB[kc], B1, 0, 0, 0);
    }
  };

  // exp/pack/permlane/PV/dot2 on the p-state (iteration it), V+mask of tile it
  auto phaseB = [&](const uint4* vs, int it) {
#pragma unroll
    for (int g = 0; g < 4; g++) {
      const f32x16& srcA = (g < 2) ? pA0 : pA1;
      const f32x16& srcB = (g < 2) ? pB0 : pB1;
      const int o = (g & 1) * 8;
      u32 wa[4], wb[4];
#pragma unroll
      for (int s = 0; s < 4; s++) {
        wa[s] = __builtin_bit_cast(u32, __builtin_amdgcn_cvt_pkrtz(
                    __builtin_amdgcn_exp2f(srcA[o + 2 * s]),
                    __builtin_amdgcn_exp2f(srcA[o + 2 * s + 1])));
        wb[s] = __builtin_bit_cast(u32, __builtin_amdgcn_cvt_pkrtz(
                    __builtin_amdgcn_exp2f(srcB[o + 2 * s]),
                    __builtin_amdgcn_exp2f(srcB[o + 2 * s + 1])));
      }
      u32x2 rA0 = __builtin_amdgcn_permlane32_swap(wa[0], wa[2], false, false);
      u32x2 rA1 = __builtin_amdgcn_permlane32_swap(wa[1], wa[3], false, false);
      u32x2 rB0 = __builtin_amdgcn_permlane32_swap(wb[0], wb[2], false, false);
      u32x2 rB1 = __builtin_amdgcn_permlane32_swap(wb[1], wb[3], false, false);
      uint4 f4A; f4A.x = rA0[0]; f4A.y = rA1[0]; f4A.z = rA0[1]; f4A.w = rA1[1];
      uint4 f4B; f4B.x = rB0[0]; f4B.y = rB1[0]; f4B.z = rB0[1]; f4B.w = rB1[1];
      f16x8 fA = __builtin_bit_cast(f16x8, f4A);
      f16x8 fB = __builtin_bit_cast(f16x8, f4B);
      f16x8 bv0 = *(const f16x8*)&vs[idxA[g]];
      f16x8 bv1 = *(const f16x8*)&vs[idxB[g]];
      const uint4 bmw = *(const uint4*)&MsAll[it * 64 + g * 16 + hi * 8];
      accO0A = __builtin_amdgcn_mfma_f32_32x32x16_f16(fA, bv0, accO0A, 0, 0, 0);
      accO1A = __builtin_amdgcn_mfma_f32_32x32x16_f16(fA, bv1, accO1A, 0, 0, 0);
      accO0B = __builtin_amdgcn_mfma_f32_32x32x16_f16(fB, bv0, accO0B, 0, 0, 0);
      accO1B = __builtin_amdgcn_mfma_f32_32x32x16_f16(fB, bv1, accO1B, 0, 0, 0);
      lAp[0] = dot2acc(f4A.x, bmw.x, lAp[0]);
      lAp[1] = dot2acc(f4A.y, bmw.y, lAp[1]);
      lAp[2] = dot2acc(f4A.z, bmw.z, lAp[2]);
      lAp[3] = dot2acc(f4A.w, bmw.w, lAp[3]);
      lBp[0] = dot2acc(f4B.x, bmw.x, lBp[0]);
      lBp[1] = dot2acc(f4B.y, bmw.y, lBp[1]);
      lBp[2] = dot2acc(f4B.z, bmw.z, lBp[2]);
      lBp[3] = dot2acc(f4B.w, bmw.w, lBp[3]);
    }
  };

  // prologue: S(0) from buf0 (resident after syncthreads)
  qkt(&Ks4[0][0], pA0, pA1, pB0, pB1);

  const int NT = S_LEN / 64;
  for (int it = 0; it < NT - 1; ++it) {
    asm volatile("s_waitcnt vmcnt(0)" ::: "memory");   // all stages landed (buf it, it+1 resident)
    __builtin_amdgcn_s_barrier();                      // all waves done with buf it-1's data
    __builtin_amdgcn_sched_barrier(0);
    const int cur = it % 3, nxt = (it + 1) % 3;
    if (it + 2 < NT) stage((it + 2) % 3);              // overwrites buf it-1; flies under body
    // pipelined body: QK^T(it+1) [MFMA] interleaved with exp/PV/dot2(it) [VALU+TRANS+MFMA]
    f32x16 nA0 = {}, nA1 = {}, nB0 = {}, nB1 = {};
    qkt(&Ks4[nxt][0], nA0, nA1, nB0, nB1);
    phaseB(&Vs4[cur][0], it);
    pA0 = nA0; pA1 = nA1; pB0 = nB0; pB1 = nB1;
  }
  // peeled final iteration: no stage, no barrier needed (reads-only, buffer resident)
  phaseB(&Vs4[(NT - 1) % 3][0], NT - 1);

  // ---- epilogue ----
  // merge split partials, then partner t-half via __shfl_xor (NOT permlane32_swap(x,x)).
  float lA = (lAp[0] + lAp[1]) + (lAp[2] + lAp[3]);
  float lB = (lBp[0] + lBp[1]) + (lBp[2] + lBp[3]);
  float lAf = lA + __shfl_xor(lA, 32, 64);
  float lBf = lB + __shfl_xor(lB, 32, 64);
  float invA = (lAf > 0.f) ? 1.f / lAf : 0.f;   // lane holds 1/l for q = l31
  float invB = (lBf > 0.f) ? 1.f / lBf : 0.f;
#pragma unroll
  for (int r = 0; r < 16; r++) {
    int qr = (r & 3) + 8 * (r >> 2) + 4 * hi;
    float iA = __builtin_bit_cast(float,
        (u32)__builtin_amdgcn_ds_bpermute(qr << 2, (int)__builtin_bit_cast(u32, invA)));
    float iB = __builtin_bit_cast(float,
        (u32)__builtin_amdgcn_ds_bpermute(qr << 2, (int)__builtin_bit_cast(u32, invB)));
    float* opA = out + ((size_t)(b * S_LEN + q0 + qr) * DMODEL) + h * DHEAD;
    float* opB = out + ((size_t)(b * S_LEN + q0 + 32 + qr) * DMODEL) + h * DHEAD;
    opA[l31] = accO0A[r] * iA;
    opA[32 + l31] = accO1A[r] * iA;
    opB[l31] = accO0B[r] * iB;
    opB[32 + l31] = accO1B[r] * iB;
  }
}

extern "C" void kernel_launch(void* const* d_in, const int* in_sizes, int n_in,
                              void* d_out, int out_size, void* d_ws, size_t ws_size,
                              hipStream_t stream) {
  const float* x    = (const float*)d_in[0];
  const float* mask = (const float*)d_in[1];
  const float* Wq   = (const float*)d_in[2];
  const float* bq   = (const float*)d_in[3];
  const float* Wk   = (const float*)d_in[4];
  const float* bk   = (const float*)d_in[5];
  const float* Wv   = (const float*)d_in[6];
  const float* bv   = (const float*)d_in[7];
  float* out = (float*)d_out;

  u16* xb = (u16*)d_ws;                         // [8192][1024] f16
  u16* wt = xb + (size_t)8192 * 1024;           // [3072][1024] f16 (W^T, q|k|v)
  u16* Qb = wt + (size_t)3072 * 1024;           // [4][16][2048][64]
  u16* Kb = Qb + (size_t)8388608;               // [4][16][2048][64]
  u16* Vb = Kb + (size_t)8388608;               // [4][16][64][2048] (mask-zeroed)

  prep<<<5120, 256, 0, stream>>>(x, xb, Wq, Wk, Wv, wt);
  qkv_gemm<<<dim3(64, 24), 256, 0, stream>>>(xb, wt, bq, bk, bv, mask, Qb, Kb, Vb);
  attn<<<512, 256, 0, stream>>>(Qb, Kb, Vb, mask, out);
}